// Round 6
// baseline (354.934 us; speedup 1.0000x reference)
//
#include <hip/hip_runtime.h>

#define NN 100000
#define NE 1600000
#define D 128
#define BN_EPS 1e-5f

#define NB 782        // ceil(NN / 128) buckets, bucket = dst >> 7
#define NWG_BIN 200   // workgroups in hist/scatter passes
#define CHUNK 8000    // NE / NWG_BIN, exact
#define ZOFF (NN*64)  // u32-offset of the zero row in H

typedef __attribute__((ext_vector_type(4))) _Float16 f16x4;
typedef __attribute__((ext_vector_type(4))) float f32x4;

static __device__ __forceinline__ float frelu(float x){ return x > 0.f ? x : 0.f; }

// bf16 helpers (RNE pack, cheap unpack)
static __device__ __forceinline__ unsigned short f2bf(float f){
  unsigned int u = __float_as_uint(f);
  u += 0x7fffu + ((u >> 16) & 1u);
  return (unsigned short)(u >> 16);
}
static __device__ __forceinline__ float bflo(unsigned int p){ return __uint_as_float(p << 16); }
static __device__ __forceinline__ float bfhi(unsigned int p){ return __uint_as_float(p & 0xffff0000u); }

// ---------------- init: zero BN sums + zero sentinel row NN of H ----------------
__global__ void k_init(float* __restrict__ colsum, unsigned int* __restrict__ hw){
  int i = threadIdx.x;
  if (i < 2*D) colsum[i] = 0.f;
  if (i < 64) hw[ZOFF + i] = 0u;   // zero row stays valid for both layers
}

// ---------------- pack W (f32 row-major [k][n]) into f16 MFMA B-fragment order ----
__global__ __launch_bounds__(256) void k_wprep(const float* __restrict__ W1f, const float* __restrict__ W2f,
                                               unsigned long long* __restrict__ P1, unsigned long long* __restrict__ P2){
  const float* W = blockIdx.x ? W2f : W1f;
  unsigned long long* P = blockIdx.x ? P2 : P1;
  int t = threadIdx.x;
  for (int i = 0; i < 16; i++){
    int s = t*16 + i;
    int l = s & 63, kt = (s >> 6) & 7, nt = s >> 9;
    int krow = kt*16 + ((l >> 4) << 2);
    int col = nt*16 + (l & 15);
    f16x4 v;
    #pragma unroll
    for (int j = 0; j < 4; j++) v[j] = (_Float16)W[(krow + j)*D + col];
    P[s] = __builtin_bit_cast(unsigned long long, v);
  }
}

// ---------------- CSR build, pass 1: per-WG bucket histogram (LDS only) ------
__global__ __launch_bounds__(256) void kb_hist(const int* __restrict__ ei, int* __restrict__ wgHist){
  __shared__ int hist[NB];
  int tid = threadIdx.x, w = blockIdx.x;
  for (int i = tid; i < NB; i += 256) hist[i] = 0;
  __syncthreads();
  int base = w*CHUNK;
  for (int e = base + tid; e < base + CHUNK; e += 256)
    atomicAdd(&hist[ei[NE + e] >> 7], 1);
  __syncthreads();
  for (int i = tid; i < NB; i += 256) wgHist[w*NB + i] = hist[i];
}

// ---- pass 2a: for each bucket, exclusive scan across WGs + bucket totals ----
__global__ __launch_bounds__(256) void kb_scan(int* __restrict__ wgHist, int* __restrict__ bucketTotal){
  __shared__ int lds[256];
  int b = blockIdx.x, t = threadIdx.x;
  int v = (t < NWG_BIN) ? wgHist[t*NB + b] : 0;
  lds[t] = v; __syncthreads();
  for (int off = 1; off < 256; off <<= 1){
    int u = (t >= off) ? lds[t - off] : 0;
    __syncthreads(); lds[t] += u; __syncthreads();
  }
  if (t < NWG_BIN) wgHist[t*NB + b] = lds[t] - v;  // exclusive along w
  if (t == 255) bucketTotal[b] = lds[255];
}

// ---- pass 2b: exclusive scan of bucket totals -> bucketStart[0..NB] ---------
__global__ __launch_bounds__(256) void kb_scan2(const int* __restrict__ bucketTotal, int* __restrict__ bucketStart){
  __shared__ int lds[256];
  int t = threadIdx.x;
  int v[4]; int s = 0;
  #pragma unroll
  for (int j = 0; j < 4; j++){ int i = t*4 + j; v[j] = (i < NB) ? bucketTotal[i] : 0; s += v[j]; }
  lds[t] = s; __syncthreads();
  for (int off = 1; off < 256; off <<= 1){
    int u = (t >= off) ? lds[t - off] : 0;
    __syncthreads(); lds[t] += u; __syncthreads();
  }
  int ex = lds[t] - s;
  #pragma unroll
  for (int j = 0; j < 4; j++){ int i = t*4 + j; if (i <= NB) bucketStart[i] = ex; ex += v[j]; }
}

// ---- pass 3: scatter edges into bucket-sorted array; pack (src<<7)|(dst&127) ----
__global__ __launch_bounds__(256) void kb_scatter(const int* __restrict__ ei, const int* __restrict__ wgHist,
                                                  const int* __restrict__ bucketStart, unsigned int* __restrict__ binned){
  __shared__ int fillB[NB];
  __shared__ int baseB[NB];
  int tid = threadIdx.x, w = blockIdx.x;
  for (int i = tid; i < NB; i += 256){ fillB[i] = 0; baseB[i] = bucketStart[i] + wgHist[w*NB + i]; }
  __syncthreads();
  int base = w*CHUNK;
  for (int e = base + tid; e < base + CHUNK; e += 256){
    int s = ei[e], d = ei[NE + e];
    int b = d >> 7;
    int r = atomicAdd(&fillB[b], 1);
    binned[baseB[b] + r] = ((unsigned)s << 7) | (unsigned)(d & 127);
  }
}

// ---- pass 4: per-bucket -> cnt, padded rowStart, dinv, colIdx (src*64, pad=ZOFF) ----
__global__ __launch_bounds__(256) void kb_node(const unsigned int* __restrict__ binned, const int* __restrict__ bucketStart,
                                               int* __restrict__ cnt, int* __restrict__ rowStart,
                                               float* __restrict__ dinv, int* __restrict__ colIdx){
  __shared__ int ncnt[128], roff[128], nfill[128];
  int b = blockIdx.x, t = threadIdx.x;
  int s0 = bucketStart[b], s1 = bucketStart[b + 1];
  int node0 = b << 7;
  int nNodes = min(128, NN - node0);
  if (t < 128){ ncnt[t] = 0; nfill[t] = 0; }
  __syncthreads();
  for (int e = s0 + t; e < s1; e += 256)
    atomicAdd(&ncnt[binned[e] & 127], 1);
  __syncthreads();
  if (t < 128) roff[t] = ncnt[t];
  __syncthreads();
  for (int off = 1; off < 128; off <<= 1){
    int u = (t >= off && t < 128) ? roff[t - off] : 0;
    __syncthreads(); if (t < 128) roff[t] += u; __syncthreads();
  }
  if (t < nNodes){
    int n = ncnt[t];
    int padBase = s0 + (roff[t] - n) + 7*(node0 + t);
    rowStart[node0 + t] = padBase;
    cnt[node0 + t] = n;
    dinv[node0 + t] = rsqrtf((float)(n + 1));
    int nP = (n + 7) & ~7;
    for (int i = n; i < nP; i++) colIdx[padBase + i] = ZOFF;  // zero-row sentinel
  }
  __syncthreads();
  for (int e = s0 + t; e < s1; e += 256){
    unsigned int ed = binned[e];
    int l = ed & 127;
    int r = atomicAdd(&nfill[l], 1);
    colIdx[s0 + (roff[l] - ncnt[l]) + 7*(node0 + l) + r] = (int)((ed >> 7) << 6);  // src*64
  }
}

// ---------------- GEMM layer 1: H[r] = bf16( dinv[r] * (X[r] @ W) ), f32 input ----
__global__ __launch_bounds__(256) void k_gemm1(const float* __restrict__ X,
                                               const unsigned long long* __restrict__ Wpk,
                                               const float* __restrict__ dinv,
                                               unsigned short* __restrict__ H){
  int tid = threadIdx.x, lane = tid & 63;
  int row0 = blockIdx.x*64 + (tid >> 6)*16;
  int arow = row0 + (lane & 15); if (arow >= NN) arow = NN - 1;
  int kg = lane >> 4;  // 0..3

  const float4* X4 = (const float4*)X;
  f16x4 a[8];
  #pragma unroll
  for (int kt = 0; kt < 8; kt++){
    float4 xv = X4[(size_t)arow*32 + kt*4 + kg];
    f16x4 av;
    av[0] = (_Float16)xv.x; av[1] = (_Float16)xv.y;
    av[2] = (_Float16)xv.z; av[3] = (_Float16)xv.w;
    a[kt] = av;
  }

  f32x4 acc[8];
  #pragma unroll
  for (int nt = 0; nt < 8; nt++){ acc[nt][0] = 0.f; acc[nt][1] = 0.f; acc[nt][2] = 0.f; acc[nt][3] = 0.f; }

  #pragma unroll
  for (int kt = 0; kt < 8; kt++){
    #pragma unroll
    for (int nt = 0; nt < 8; nt++){
      f16x4 bfr = __builtin_bit_cast(f16x4, Wpk[(nt*8 + kt)*64 + lane]);
      acc[nt] = __builtin_amdgcn_mfma_f32_16x16x16f16(a[kt], bfr, acc[nt], 0, 0, 0);
    }
  }

  int rbase = row0 + kg*4;
  float4 dv = *(const float4*)&dinv[rbase];
  #pragma unroll
  for (int r = 0; r < 4; r++){
    int row = rbase + r;
    if (row < NN){
      float sc = (r == 0) ? dv.x : (r == 1) ? dv.y : (r == 2) ? dv.z : dv.w;
      #pragma unroll
      for (int nt = 0; nt < 8; nt++)
        H[(size_t)row*D + nt*16 + (lane & 15)] = f2bf(acc[nt][r]*sc);
    }
  }
}

// ---------------- GEMM layer 2: input = relu(gb*aggb + bb); also emits o1 (f32) ----
__global__ __launch_bounds__(256) void k_gemm2(const unsigned int* __restrict__ A,
                                               const float* __restrict__ gb, const float* __restrict__ bb,
                                               const unsigned long long* __restrict__ Wpk,
                                               const float* __restrict__ dinv,
                                               unsigned short* __restrict__ H,
                                               float* __restrict__ o1){
  int tid = threadIdx.x, lane = tid & 63;
  int row0 = blockIdx.x*64 + (tid >> 6)*16;
  int arow = row0 + (lane & 15); if (arow >= NN) arow = NN - 1;
  int kg = lane >> 4;  // 0..3

  const uint2* A2 = (const uint2*)A;
  f16x4 a[8];
  #pragma unroll
  for (int kt = 0; kt < 8; kt++){
    uint2 v = A2[(size_t)arow*32 + kt*4 + kg];
    int c0 = kt*16 + kg*4;
    float4 g = *(const float4*)&gb[c0];
    float4 bo = *(const float4*)&bb[c0];
    float r0 = frelu(bflo(v.x)*g.x + bo.x);
    float r1 = frelu(bfhi(v.x)*g.y + bo.y);
    float r2 = frelu(bflo(v.y)*g.z + bo.z);
    float r3 = frelu(bfhi(v.y)*g.w + bo.w);
    *(float4*)&o1[(size_t)arow*D + c0] = make_float4(r0, r1, r2, r3);  // fused BN+ReLU output
    f16x4 av;
    av[0] = (_Float16)r0; av[1] = (_Float16)r1; av[2] = (_Float16)r2; av[3] = (_Float16)r3;
    a[kt] = av;
  }

  f32x4 acc[8];
  #pragma unroll
  for (int nt = 0; nt < 8; nt++){ acc[nt][0] = 0.f; acc[nt][1] = 0.f; acc[nt][2] = 0.f; acc[nt][3] = 0.f; }

  #pragma unroll
  for (int kt = 0; kt < 8; kt++){
    #pragma unroll
    for (int nt = 0; nt < 8; nt++){
      f16x4 bfr = __builtin_bit_cast(f16x4, Wpk[(nt*8 + kt)*64 + lane]);
      acc[nt] = __builtin_amdgcn_mfma_f32_16x16x16f16(a[kt], bfr, acc[nt], 0, 0, 0);
    }
  }

  int rbase = row0 + kg*4;
  float4 dv = *(const float4*)&dinv[rbase];
  #pragma unroll
  for (int r = 0; r < 4; r++){
    int row = rbase + r;
    if (row < NN){
      float sc = (r == 0) ? dv.x : (r == 1) ? dv.y : (r == 2) ? dv.z : dv.w;
      #pragma unroll
      for (int nt = 0; nt < 8; nt++)
        H[(size_t)row*D + nt*16 + (lane & 15)] = f2bf(acc[nt][r]*sc);
    }
  }
}

// ---------------- aggregate: one wave per node, scalar CSR walk + saddr gathers ----
// colIdx pre-scaled (src*64) and padded to x8 with ZOFF (zero row). All control
// state (beg, n) forced to SGPRs -> colIdx reads become s_load, gathers are the
// only VMEM. Per edge: 1 VMEM + 1/8 SMEM + ~3 VALU.
__global__ __launch_bounds__(256) void k_agg(const unsigned int* __restrict__ Hp,
                                             const float* __restrict__ dinv,
                                             const int* __restrict__ rowStart,
                                             const int* __restrict__ cnt,
                                             const int* __restrict__ colIdx,
                                             unsigned int* __restrict__ outb){
  int node = blockIdx.x*4 + (threadIdx.x >> 6);
  int lane = threadIdx.x & 63;

  int beg = __builtin_amdgcn_readfirstlane(rowStart[node]);
  int n   = __builtin_amdgcn_readfirstlane(cnt[node]);
  int nP  = (n + 7) & ~7;
  const int* cp = colIdx + beg;

  float di = dinv[node];
  unsigned int sv = Hp[node*64 + lane];   // self (pre-scaled by its dinv)
  float2 a0 = make_float2(bflo(sv), bfhi(sv));
  float2 a1 = make_float2(0.f, 0.f), a2 = a1, a3 = a1;
  float2 a4 = a1, a5 = a1, a6 = a1, a7 = a1;

  for (int j = 0; j < nP; j += 8){
    int i0 = cp[j  ], i1 = cp[j+1], i2 = cp[j+2], i3 = cp[j+3];
    int i4 = cp[j+4], i5 = cp[j+5], i6 = cp[j+6], i7 = cp[j+7];
    unsigned int v0 = Hp[i0 + lane];
    unsigned int v1 = Hp[i1 + lane];
    unsigned int v2 = Hp[i2 + lane];
    unsigned int v3 = Hp[i3 + lane];
    unsigned int v4 = Hp[i4 + lane];
    unsigned int v5 = Hp[i5 + lane];
    unsigned int v6 = Hp[i6 + lane];
    unsigned int v7 = Hp[i7 + lane];
    a0.x += bflo(v0); a0.y += bfhi(v0);
    a1.x += bflo(v1); a1.y += bfhi(v1);
    a2.x += bflo(v2); a2.y += bfhi(v2);
    a3.x += bflo(v3); a3.y += bfhi(v3);
    a4.x += bflo(v4); a4.y += bfhi(v4);
    a5.x += bflo(v5); a5.y += bfhi(v5);
    a6.x += bflo(v6); a6.y += bfhi(v6);
    a7.x += bflo(v7); a7.y += bfhi(v7);
  }

  float sx = ((a0.x + a1.x) + (a2.x + a3.x)) + ((a4.x + a5.x) + (a6.x + a7.x));
  float sy = ((a0.y + a1.y) + (a2.y + a3.y)) + ((a4.y + a5.y) + (a6.y + a7.y));
  unsigned int pk = (unsigned int)f2bf(di*sx) | ((unsigned int)f2bf(di*sy) << 16);
  outb[node*64 + lane] = pk;
}

// ---------------- BN column sums over bf16 agg ----------------
__global__ __launch_bounds__(256) void k_bnreduce(const unsigned int* __restrict__ A, float* __restrict__ colsum){
  int tid = threadIdx.x;
  int c2 = tid & 63;   // column pair (2c2, 2c2+1)
  int rg = tid >> 6;   // 0..3
  float slo = 0.f, shi = 0.f, qlo = 0.f, qhi = 0.f;
  for (int r = blockIdx.x*4 + rg; r < NN; r += gridDim.x*4){
    unsigned int v = A[(size_t)r*64 + c2];
    float lo = bflo(v), hi = bfhi(v);
    slo += lo; shi += hi; qlo += lo*lo; qhi += hi*hi;
  }
  __shared__ float2 lds[256];
  lds[tid] = make_float2(slo, qlo); __syncthreads();
  if (rg == 0){
    float2 b = lds[c2 + 64], c = lds[c2 + 128], d = lds[c2 + 192];
    atomicAdd(&colsum[2*c2],     slo + b.x + c.x + d.x);
    atomicAdd(&colsum[D + 2*c2], qlo + b.y + c.y + d.y);
  }
  __syncthreads();
  lds[tid] = make_float2(shi, qhi); __syncthreads();
  if (rg == 0){
    float2 b = lds[c2 + 64], c = lds[c2 + 128], d = lds[c2 + 192];
    atomicAdd(&colsum[2*c2 + 1],     shi + b.x + c.x + d.x);
    atomicAdd(&colsum[D + 2*c2 + 1], qhi + b.y + c.y + d.y);
  }
}

// mu/rstd -> folded gb/bb, then zero partial sums for next layer/call
__global__ void k_bnfinal(float* __restrict__ colsum, const float* __restrict__ gamma,
                          const float* __restrict__ beta, float* __restrict__ gb, float* __restrict__ bb){
  int c = threadIdx.x;
  float mu = colsum[c] * (1.f / NN);
  float var = colsum[D + c] * (1.f / NN) - mu*mu;
  float g = gamma[c] * rsqrtf(var + BN_EPS);
  gb[c] = g;
  bb[c] = beta[c] - mu*g;
  colsum[c] = 0.f; colsum[D + c] = 0.f;
}

// ---------------- BN apply + ReLU: bf16 agg -> f32 out (layer 2 only) ----------
__global__ __launch_bounds__(256) void k_bnapply(const unsigned int* __restrict__ A, const float* __restrict__ gb,
                                                 const float* __restrict__ bb, float* __restrict__ out){
  int idx = blockIdx.x*256 + threadIdx.x;
  if (idx >= NN*64) return;
  unsigned int v = A[idx];
  int c2 = idx & 63;
  float2 g = ((const float2*)gb)[c2];
  float2 b = ((const float2*)bb)[c2];
  float lo = frelu(bflo(v)*g.x + b.x);
  float hi = frelu(bfhi(v)*g.y + b.y);
  ((float2*)out)[idx] = make_float2(lo, hi);
}

extern "C" void kernel_launch(void* const* d_in, const int* in_sizes, int n_in,
                              void* d_out, int out_size, void* d_ws, size_t ws_size,
                              hipStream_t stream){
  const float* x   = (const float*)d_in[0];
  const int*   ei  = (const int*)d_in[1];   // [2][NE], row0 = src, row1 = dst
  const float* W1  = (const float*)d_in[2];
  const float* g1  = (const float*)d_in[4];
  const float* be1 = (const float*)d_in[5];
  const float* W2  = (const float*)d_in[6];
  const float* g2  = (const float*)d_in[8];
  const float* be2 = (const float*)d_in[9];
  // b1/b2 cancel exactly inside BatchNorm (agg+b - mean(agg+b)) -> skipped.

  float* out = (float*)d_out;
  float* o1 = out;
  float* o2 = out + (size_t)NN*D;

  char* ws = (char*)d_ws;
  int*   cnt         = (int*)(ws + 0);           // 400000 B
  int*   rowStart    = (int*)(ws + 400384);      // 400000 B (padded starts)
  float* dinv        = (float*)(ws + 800768);    // 400000 B
  float* colsum      = (float*)(ws + 1201152);   // 1024 B
  float* gb          = (float*)(ws + 1202176);   // 512 B
  float* bb          = (float*)(ws + 1202688);   // 512 B
  int*   bucketTotal = (int*)(ws + 1203200);     // 3128 B
  int*   bucketStart = (int*)(ws + 1206400);     // 3132 B
  int*   wgHist      = (int*)(ws + 1209600);     // 625600 B
  unsigned long long* Wpk1 = (unsigned long long*)(ws + 1835264);  // 32768 B
  unsigned long long* Wpk2 = (unsigned long long*)(ws + 1868288);  // 32768 B
  int*   colIdx      = (int*)(ws + 1901312);     // (NE+7*NN+256)*4 = 9201024 B
  unsigned int* binned = (unsigned int*)(ws + 11102336);  // 6.4 MB
  unsigned int* aggb = (unsigned int*)(ws + 17502336);    // 25.6 MB (bf16 agg)
  unsigned short* h  = (unsigned short*)(ws + 43102336);  // 25.6 MB + 256 B zero row
  // total ~68.7 MB of ws

  // ---- prep: W fragment packing + graph counting-sort ----
  k_init    <<<1, 256, 0, stream>>>(colsum, (unsigned int*)h);
  k_wprep   <<<2, 256, 0, stream>>>(W1, W2, Wpk1, Wpk2);
  kb_hist   <<<NWG_BIN, 256, 0, stream>>>(ei, wgHist);
  kb_scan   <<<NB, 256, 0, stream>>>(wgHist, bucketTotal);
  kb_scan2  <<<1, 256, 0, stream>>>(bucketTotal, bucketStart);
  kb_scatter<<<NWG_BIN, 256, 0, stream>>>(ei, wgHist, bucketStart, binned);
  kb_node   <<<NB, 256, 0, stream>>>(binned, bucketStart, cnt, rowStart, dinv, colIdx);

  // ---- layer 1 ----
  k_gemm1   <<<(NN + 63)/64, 256, 0, stream>>>(x, Wpk1, dinv, h);
  k_agg     <<<NN/4, 256, 0, stream>>>((const unsigned int*)h, dinv, rowStart, cnt, colIdx, aggb);
  k_bnreduce<<<512, 256, 0, stream>>>(aggb, colsum);
  k_bnfinal <<<1, 128, 0, stream>>>(colsum, g1, be1, gb, bb);

  // ---- layer 2 (gemm reads bf16 agg, applies BN+ReLU inline, emits o1) ----
  k_gemm2   <<<(NN + 63)/64, 256, 0, stream>>>(aggb, gb, bb, Wpk2, dinv, h, o1);
  k_agg     <<<NN/4, 256, 0, stream>>>((const unsigned int*)h, dinv, rowStart, cnt, colIdx, aggb);
  k_bnreduce<<<512, 256, 0, stream>>>(aggb, colsum);
  k_bnfinal <<<1, 128, 0, stream>>>(colsum, g2, be2, gb, bb);
  k_bnapply <<<(NN*64 + 255)/256, 256, 0, stream>>>(aggb, gb, bb, o2);
}

// Round 7
// 350.682 us; speedup vs baseline: 1.0121x; 1.0121x over previous
//
#include <hip/hip_runtime.h>

#define NN 100000
#define NE 1600000
#define D 128
#define BN_EPS 1e-5f

#define NB 782        // ceil(NN / 128) buckets, bucket = dst >> 7
#define NBP 784       // padded bucket count (x4-per-thread scan)
#define NWG_BIN 200   // workgroups in sort pass
#define CHUNK 8000    // NE / NWG_BIN, exact
#define ZOFF (NN*64)  // u32-offset of the zero row in H

typedef __attribute__((ext_vector_type(4))) _Float16 f16x4;
typedef __attribute__((ext_vector_type(4))) float f32x4;

static __device__ __forceinline__ float frelu(float x){ return x > 0.f ? x : 0.f; }

// bf16 helpers (RNE pack, cheap unpack)
static __device__ __forceinline__ unsigned short f2bf(float f){
  unsigned int u = __float_as_uint(f);
  u += 0x7fffu + ((u >> 16) & 1u);
  return (unsigned short)(u >> 16);
}
static __device__ __forceinline__ float bflo(unsigned int p){ return __uint_as_float(p << 16); }
static __device__ __forceinline__ float bfhi(unsigned int p){ return __uint_as_float(p & 0xffff0000u); }

// ---------------- prep: zero colsum/bucketCnt/zero-row + pack W1/W2 ----------------
__global__ __launch_bounds__(256) void k_prep(const float* __restrict__ W1f, const float* __restrict__ W2f,
                                              unsigned long long* __restrict__ P1, unsigned long long* __restrict__ P2,
                                              float* __restrict__ colsum, unsigned int* __restrict__ hw,
                                              int* __restrict__ bucketCnt){
  int t = threadIdx.x;
  if (blockIdx.x == 0){
    colsum[t] = 0.f;                      // 256 = 2*D
    if (t < 64) hw[ZOFF + t] = 0u;        // zero sentinel row
    for (int i = t; i < NB; i += 256) bucketCnt[i] = 0;
    return;
  }
  const float* W = (blockIdx.x == 2) ? W2f : W1f;
  unsigned long long* P = (blockIdx.x == 2) ? P2 : P1;
  for (int i = 0; i < 16; i++){
    int s = t*16 + i;
    int l = s & 63, kt = (s >> 6) & 7, nt = s >> 9;
    int krow = kt*16 + ((l >> 4) << 2);
    int col = nt*16 + (l & 15);
    f16x4 v;
    #pragma unroll
    for (int j = 0; j < 4; j++) v[j] = (_Float16)W[(krow + j)*D + col];
    P[s] = __builtin_bit_cast(unsigned long long, v);
  }
}

// ---------------- build pass 1: per-WG local counting sort into own region ------
// WG w: hist over 782 buckets, LDS exclusive scan, scatter chunk edges into
// binned[w*CHUNK .. w*CHUNK+8000) ordered by bucket (coalesced region), write
// local offsets wgLoc[w][0..783) (lofs[782]=8000 sentinel), atomadd bucketCnt.
__global__ __launch_bounds__(256) void kb_sort1(const int* __restrict__ ei,
                                                int* __restrict__ wgLoc, int* __restrict__ bucketCnt,
                                                unsigned int* __restrict__ binned){
  __shared__ int hist[NBP];
  __shared__ int lofs[NBP];
  __shared__ int fill[NBP];
  __shared__ int tsum[256];
  int t = threadIdx.x, w = blockIdx.x;
  for (int i = t; i < NBP; i += 256){ hist[i] = 0; fill[i] = 0; }
  __syncthreads();

  int base = w*CHUNK;
  for (int e = base + t; e < base + CHUNK; e += 256)
    atomicAdd(&hist[ei[NE + e] >> 7], 1);
  __syncthreads();

  // exclusive scan over 784 buckets: 4 per thread (t<196) + scan of 256 partials
  int b0 = t*4;
  int h0 = 0, h1 = 0, h2 = 0, h3 = 0, s = 0;
  if (b0 < NBP){
    h0 = hist[b0]; h1 = hist[b0+1]; h2 = hist[b0+2]; h3 = hist[b0+3];
    s = h0 + h1 + h2 + h3;
  }
  tsum[t] = s; __syncthreads();
  for (int off = 1; off < 256; off <<= 1){
    int u = (t >= off) ? tsum[t - off] : 0;
    __syncthreads(); tsum[t] += u; __syncthreads();
  }
  if (b0 < NBP){
    int ex = tsum[t] - s;
    lofs[b0] = ex; lofs[b0+1] = ex + h0; lofs[b0+2] = ex + h0 + h1; lofs[b0+3] = ex + h0 + h1 + h2;
  }
  __syncthreads();

  // persist local offsets (783 entries incl. sentinel = 8000) + bucket totals
  for (int i = t; i < NB + 1; i += 256) wgLoc[w*NBP + i] = lofs[i];
  for (int i = t; i < NB; i += 256) if (hist[i]) atomicAdd(&bucketCnt[i], hist[i]);

  // scatter pass: re-read chunk, place into local region by bucket
  for (int e = base + t; e < base + CHUNK; e += 256){
    int sc = ei[e], d = ei[NE + e];
    int b = d >> 7;
    int r = atomicAdd(&fill[b], 1);
    binned[base + lofs[b] + r] = ((unsigned)sc << 7) | (unsigned)(d & 127);
  }
}

// ---- pass 2: exclusive scan of bucket totals -> bucketStart[0..NB] ---------
__global__ __launch_bounds__(256) void kb_scan2(const int* __restrict__ bucketCnt, int* __restrict__ bucketStart){
  __shared__ int lds[256];
  int t = threadIdx.x;
  int v[4]; int s = 0;
  #pragma unroll
  for (int j = 0; j < 4; j++){ int i = t*4 + j; v[j] = (i < NB) ? bucketCnt[i] : 0; s += v[j]; }
  lds[t] = s; __syncthreads();
  for (int off = 1; off < 256; off <<= 1){
    int u = (t >= off) ? lds[t - off] : 0;
    __syncthreads(); lds[t] += u; __syncthreads();
  }
  int ex = lds[t] - s;
  #pragma unroll
  for (int j = 0; j < 4; j++){ int i = t*4 + j; if (i <= NB) bucketStart[i] = ex; ex += v[j]; }
}

// ---- pass 3: per-bucket node build from 200 fragments -> cnt/rowStart/dinv/colIdx ----
// fragment w of bucket b = binned[w*CHUNK + wgLoc[w][b] .. w*CHUNK + wgLoc[w][b+1])
__global__ __launch_bounds__(256) void kb_node2(const unsigned int* __restrict__ binned,
                                                const int* __restrict__ wgLoc,
                                                const int* __restrict__ bucketStart,
                                                int* __restrict__ cnt, int* __restrict__ rowStart,
                                                float* __restrict__ dinv, int* __restrict__ colIdx){
  __shared__ int ncnt[128], roff[128], nfill[128];
  int b = blockIdx.x, t = threadIdx.x;
  int s0 = bucketStart[b];
  int node0 = b << 7;
  int nNodes = min(128, NN - node0);
  if (t < 128){ ncnt[t] = 0; nfill[t] = 0; }
  __syncthreads();

  int fb = 0, fe = 0;
  if (t < NWG_BIN){
    fb = t*CHUNK + wgLoc[t*NBP + b];
    fe = t*CHUNK + wgLoc[t*NBP + b + 1];
    for (int e = fb; e < fe; e++)
      atomicAdd(&ncnt[binned[e] & 127], 1);
  }
  __syncthreads();
  if (t < 128) roff[t] = ncnt[t];
  __syncthreads();
  for (int off = 1; off < 128; off <<= 1){
    int u = (t >= off && t < 128) ? roff[t - off] : 0;
    __syncthreads(); if (t < 128) roff[t] += u; __syncthreads();
  }
  if (t < nNodes){
    int n = ncnt[t];
    int padBase = s0 + (roff[t] - n) + 7*(node0 + t);
    rowStart[node0 + t] = padBase;
    cnt[node0 + t] = n;
    dinv[node0 + t] = rsqrtf((float)(n + 1));
    int nP = (n + 7) & ~7;
    for (int i = n; i < nP; i++) colIdx[padBase + i] = ZOFF;  // zero-row sentinel
  }
  __syncthreads();
  if (t < NWG_BIN){
    for (int e = fb; e < fe; e++){
      unsigned int ed = binned[e];
      int l = ed & 127;
      int r = atomicAdd(&nfill[l], 1);
      colIdx[s0 + (roff[l] - ncnt[l]) + 7*(node0 + l) + r] = (int)((ed >> 7) << 6);  // src*64
    }
  }
}

// ---------------- GEMM layer 1: H[r] = bf16( dinv[r] * (X[r] @ W) ), f32 input ----
__global__ __launch_bounds__(256) void k_gemm1(const float* __restrict__ X,
                                               const unsigned long long* __restrict__ Wpk,
                                               const float* __restrict__ dinv,
                                               unsigned short* __restrict__ H){
  int tid = threadIdx.x, lane = tid & 63;
  int row0 = blockIdx.x*64 + (tid >> 6)*16;
  int arow = row0 + (lane & 15); if (arow >= NN) arow = NN - 1;
  int kg = lane >> 4;  // 0..3

  const float4* X4 = (const float4*)X;
  f16x4 a[8];
  #pragma unroll
  for (int kt = 0; kt < 8; kt++){
    float4 xv = X4[(size_t)arow*32 + kt*4 + kg];
    f16x4 av;
    av[0] = (_Float16)xv.x; av[1] = (_Float16)xv.y;
    av[2] = (_Float16)xv.z; av[3] = (_Float16)xv.w;
    a[kt] = av;
  }

  f32x4 acc[8];
  #pragma unroll
  for (int nt = 0; nt < 8; nt++){ acc[nt][0] = 0.f; acc[nt][1] = 0.f; acc[nt][2] = 0.f; acc[nt][3] = 0.f; }

  #pragma unroll
  for (int kt = 0; kt < 8; kt++){
    #pragma unroll
    for (int nt = 0; nt < 8; nt++){
      f16x4 bfr = __builtin_bit_cast(f16x4, Wpk[(nt*8 + kt)*64 + lane]);
      acc[nt] = __builtin_amdgcn_mfma_f32_16x16x16f16(a[kt], bfr, acc[nt], 0, 0, 0);
    }
  }

  int rbase = row0 + kg*4;
  float4 dv = *(const float4*)&dinv[rbase];
  #pragma unroll
  for (int r = 0; r < 4; r++){
    int row = rbase + r;
    if (row < NN){
      float sc = (r == 0) ? dv.x : (r == 1) ? dv.y : (r == 2) ? dv.z : dv.w;
      #pragma unroll
      for (int nt = 0; nt < 8; nt++)
        H[(size_t)row*D + nt*16 + (lane & 15)] = f2bf(acc[nt][r]*sc);
    }
  }
}

// ---------------- GEMM layer 2: input = relu(gb*aggb + bb); also emits o1 (f32) ----
__global__ __launch_bounds__(256) void k_gemm2(const unsigned int* __restrict__ A,
                                               const float* __restrict__ gb, const float* __restrict__ bb,
                                               const unsigned long long* __restrict__ Wpk,
                                               const float* __restrict__ dinv,
                                               unsigned short* __restrict__ H,
                                               float* __restrict__ o1){
  int tid = threadIdx.x, lane = tid & 63;
  int row0 = blockIdx.x*64 + (tid >> 6)*16;
  int arow = row0 + (lane & 15); if (arow >= NN) arow = NN - 1;
  int kg = lane >> 4;  // 0..3

  const uint2* A2 = (const uint2*)A;
  f16x4 a[8];
  #pragma unroll
  for (int kt = 0; kt < 8; kt++){
    uint2 v = A2[(size_t)arow*32 + kt*4 + kg];
    int c0 = kt*16 + kg*4;
    float4 g = *(const float4*)&gb[c0];
    float4 bo = *(const float4*)&bb[c0];
    float r0 = frelu(bflo(v.x)*g.x + bo.x);
    float r1 = frelu(bfhi(v.x)*g.y + bo.y);
    float r2 = frelu(bflo(v.y)*g.z + bo.z);
    float r3 = frelu(bfhi(v.y)*g.w + bo.w);
    *(float4*)&o1[(size_t)arow*D + c0] = make_float4(r0, r1, r2, r3);  // fused BN+ReLU output
    f16x4 av;
    av[0] = (_Float16)r0; av[1] = (_Float16)r1; av[2] = (_Float16)r2; av[3] = (_Float16)r3;
    a[kt] = av;
  }

  f32x4 acc[8];
  #pragma unroll
  for (int nt = 0; nt < 8; nt++){ acc[nt][0] = 0.f; acc[nt][1] = 0.f; acc[nt][2] = 0.f; acc[nt][3] = 0.f; }

  #pragma unroll
  for (int kt = 0; kt < 8; kt++){
    #pragma unroll
    for (int nt = 0; nt < 8; nt++){
      f16x4 bfr = __builtin_bit_cast(f16x4, Wpk[(nt*8 + kt)*64 + lane]);
      acc[nt] = __builtin_amdgcn_mfma_f32_16x16x16f16(a[kt], bfr, acc[nt], 0, 0, 0);
    }
  }

  int rbase = row0 + kg*4;
  float4 dv = *(const float4*)&dinv[rbase];
  #pragma unroll
  for (int r = 0; r < 4; r++){
    int row = rbase + r;
    if (row < NN){
      float sc = (r == 0) ? dv.x : (r == 1) ? dv.y : (r == 2) ? dv.z : dv.w;
      #pragma unroll
      for (int nt = 0; nt < 8; nt++)
        H[(size_t)row*D + nt*16 + (lane & 15)] = f2bf(acc[nt][r]*sc);
    }
  }
}

// ---------------- aggregate: one wave per node, scalar CSR walk + saddr gathers ----
__global__ __launch_bounds__(256) void k_agg(const unsigned int* __restrict__ Hp,
                                             const float* __restrict__ dinv,
                                             const int* __restrict__ rowStart,
                                             const int* __restrict__ cnt,
                                             const int* __restrict__ colIdx,
                                             unsigned int* __restrict__ outb){
  int node = blockIdx.x*4 + (threadIdx.x >> 6);
  int lane = threadIdx.x & 63;

  int beg = __builtin_amdgcn_readfirstlane(rowStart[node]);
  int n   = __builtin_amdgcn_readfirstlane(cnt[node]);
  int nP  = (n + 7) & ~7;
  const int* cp = colIdx + beg;

  float di = dinv[node];
  unsigned int sv = Hp[node*64 + lane];   // self (pre-scaled by its dinv)
  float2 a0 = make_float2(bflo(sv), bfhi(sv));
  float2 a1 = make_float2(0.f, 0.f), a2 = a1, a3 = a1;
  float2 a4 = a1, a5 = a1, a6 = a1, a7 = a1;

  for (int j = 0; j < nP; j += 8){
    int i0 = cp[j  ], i1 = cp[j+1], i2 = cp[j+2], i3 = cp[j+3];
    int i4 = cp[j+4], i5 = cp[j+5], i6 = cp[j+6], i7 = cp[j+7];
    unsigned int v0 = Hp[i0 + lane];
    unsigned int v1 = Hp[i1 + lane];
    unsigned int v2 = Hp[i2 + lane];
    unsigned int v3 = Hp[i3 + lane];
    unsigned int v4 = Hp[i4 + lane];
    unsigned int v5 = Hp[i5 + lane];
    unsigned int v6 = Hp[i6 + lane];
    unsigned int v7 = Hp[i7 + lane];
    a0.x += bflo(v0); a0.y += bfhi(v0);
    a1.x += bflo(v1); a1.y += bfhi(v1);
    a2.x += bflo(v2); a2.y += bfhi(v2);
    a3.x += bflo(v3); a3.y += bfhi(v3);
    a4.x += bflo(v4); a4.y += bfhi(v4);
    a5.x += bflo(v5); a5.y += bfhi(v5);
    a6.x += bflo(v6); a6.y += bfhi(v6);
    a7.x += bflo(v7); a7.y += bfhi(v7);
  }

  float sx = ((a0.x + a1.x) + (a2.x + a3.x)) + ((a4.x + a5.x) + (a6.x + a7.x));
  float sy = ((a0.y + a1.y) + (a2.y + a3.y)) + ((a4.y + a5.y) + (a6.y + a7.y));
  unsigned int pk = (unsigned int)f2bf(di*sx) | ((unsigned int)f2bf(di*sy) << 16);
  outb[node*64 + lane] = pk;
}

// ---------------- BN column sums over bf16 agg ----------------
__global__ __launch_bounds__(256) void k_bnreduce(const unsigned int* __restrict__ A, float* __restrict__ colsum){
  int tid = threadIdx.x;
  int c2 = tid & 63;   // column pair (2c2, 2c2+1)
  int rg = tid >> 6;   // 0..3
  float slo = 0.f, shi = 0.f, qlo = 0.f, qhi = 0.f;
  for (int r = blockIdx.x*4 + rg; r < NN; r += gridDim.x*4){
    unsigned int v = A[(size_t)r*64 + c2];
    float lo = bflo(v), hi = bfhi(v);
    slo += lo; shi += hi; qlo += lo*lo; qhi += hi*hi;
  }
  __shared__ float2 lds[256];
  lds[tid] = make_float2(slo, qlo); __syncthreads();
  if (rg == 0){
    float2 b = lds[c2 + 64], c = lds[c2 + 128], d = lds[c2 + 192];
    atomicAdd(&colsum[2*c2],     slo + b.x + c.x + d.x);
    atomicAdd(&colsum[D + 2*c2], qlo + b.y + c.y + d.y);
  }
  __syncthreads();
  lds[tid] = make_float2(shi, qhi); __syncthreads();
  if (rg == 0){
    float2 b = lds[c2 + 64], c = lds[c2 + 128], d = lds[c2 + 192];
    atomicAdd(&colsum[2*c2 + 1],     shi + b.x + c.x + d.x);
    atomicAdd(&colsum[D + 2*c2 + 1], qhi + b.y + c.y + d.y);
  }
}

// mu/rstd -> folded gb/bb, then zero partial sums for next layer/call
__global__ void k_bnfinal(float* __restrict__ colsum, const float* __restrict__ gamma,
                          const float* __restrict__ beta, float* __restrict__ gb, float* __restrict__ bb){
  int c = threadIdx.x;
  float mu = colsum[c] * (1.f / NN);
  float var = colsum[D + c] * (1.f / NN) - mu*mu;
  float g = gamma[c] * rsqrtf(var + BN_EPS);
  gb[c] = g;
  bb[c] = beta[c] - mu*g;
  colsum[c] = 0.f; colsum[D + c] = 0.f;
}

// ---------------- BN apply + ReLU: bf16 agg -> f32 out (layer 2 only) ----------
__global__ __launch_bounds__(256) void k_bnapply(const unsigned int* __restrict__ A, const float* __restrict__ gb,
                                                 const float* __restrict__ bb, float* __restrict__ out){
  int idx = blockIdx.x*256 + threadIdx.x;
  if (idx >= NN*64) return;
  unsigned int v = A[idx];
  int c2 = idx & 63;
  float2 g = ((const float2*)gb)[c2];
  float2 b = ((const float2*)bb)[c2];
  float lo = frelu(bflo(v)*g.x + b.x);
  float hi = frelu(bfhi(v)*g.y + b.y);
  ((float2*)out)[idx] = make_float2(lo, hi);
}

extern "C" void kernel_launch(void* const* d_in, const int* in_sizes, int n_in,
                              void* d_out, int out_size, void* d_ws, size_t ws_size,
                              hipStream_t stream){
  const float* x   = (const float*)d_in[0];
  const int*   ei  = (const int*)d_in[1];   // [2][NE], row0 = src, row1 = dst
  const float* W1  = (const float*)d_in[2];
  const float* g1  = (const float*)d_in[4];
  const float* be1 = (const float*)d_in[5];
  const float* W2  = (const float*)d_in[6];
  const float* g2  = (const float*)d_in[8];
  const float* be2 = (const float*)d_in[9];
  // b1/b2 cancel exactly inside BatchNorm (agg+b - mean(agg+b)) -> skipped.

  float* out = (float*)d_out;
  float* o1 = out;
  float* o2 = out + (size_t)NN*D;

  char* ws = (char*)d_ws;
  int*   cnt         = (int*)(ws + 0);           // 400000 B
  int*   rowStart    = (int*)(ws + 400384);      // 400000 B (padded starts)
  float* dinv        = (float*)(ws + 800768);    // 400000 B
  float* colsum      = (float*)(ws + 1201152);   // 1024 B
  float* gb          = (float*)(ws + 1202176);   // 512 B
  float* bb          = (float*)(ws + 1202688);   // 512 B
  int*   bucketCnt   = (int*)(ws + 1203200);     // 3128 B
  int*   bucketStart = (int*)(ws + 1206400);     // 3132 B
  int*   wgLoc       = (int*)(ws + 1209600);     // 200*784*4 = 627200 B
  unsigned long long* Wpk1 = (unsigned long long*)(ws + 1836800);  // 32768 B
  unsigned long long* Wpk2 = (unsigned long long*)(ws + 1869568);  // 32768 B
  int*   colIdx      = (int*)(ws + 1902336);     // (NE+7*NN+256)*4 = 9201024 B
  unsigned int* binned = (unsigned int*)(ws + 11103360);  // 6.4 MB (WG-major, bucket-sorted)
  unsigned int* aggb = (unsigned int*)(ws + 17503360);    // 25.6 MB (bf16 agg)
  unsigned short* h  = (unsigned short*)(ws + 43103360);  // 25.6 MB + 256 B zero row
  // total ~68.7 MB of ws

  // ---- prep + write-coalesced counting-sort build ----
  k_prep    <<<3, 256, 0, stream>>>(W1, W2, Wpk1, Wpk2, colsum, (unsigned int*)h, bucketCnt);
  kb_sort1  <<<NWG_BIN, 256, 0, stream>>>(ei, wgLoc, bucketCnt, binned);
  kb_scan2  <<<1, 256, 0, stream>>>(bucketCnt, bucketStart);
  kb_node2  <<<NB, 256, 0, stream>>>(binned, wgLoc, bucketStart, cnt, rowStart, dinv, colIdx);

  // ---- layer 1 ----
  k_gemm1   <<<(NN + 63)/64, 256, 0, stream>>>(x, Wpk1, dinv, h);
  k_agg     <<<NN/4, 256, 0, stream>>>((const unsigned int*)h, dinv, rowStart, cnt, colIdx, aggb);
  k_bnreduce<<<512, 256, 0, stream>>>(aggb, colsum);
  k_bnfinal <<<1, 128, 0, stream>>>(colsum, g1, be1, gb, bb);

  // ---- layer 2 (gemm reads bf16 agg, applies BN+ReLU inline, emits o1) ----
  k_gemm2   <<<(NN + 63)/64, 256, 0, stream>>>(aggb, gb, bb, Wpk2, dinv, h, o1);
  k_agg     <<<NN/4, 256, 0, stream>>>((const unsigned int*)h, dinv, rowStart, cnt, colIdx, aggb);
  k_bnreduce<<<512, 256, 0, stream>>>(aggb, colsum);
  k_bnfinal <<<1, 128, 0, stream>>>(colsum, g2, be2, gb, bb);
  k_bnapply <<<(NN*64 + 255)/256, 256, 0, stream>>>(aggb, gb, bb, o2);
}

// Round 8
// 287.632 us; speedup vs baseline: 1.2340x; 1.2192x over previous
//
#include <hip/hip_runtime.h>

#define NN 100000
#define NE 1600000
#define D 128
#define BN_EPS 1e-5f

#define NB 782        // ceil(NN / 128) buckets, bucket = dst >> 7
#define NBP 784       // padded bucket count (x4-per-thread scan)
#define NWG_BIN 200   // workgroups in sort pass
#define CHUNK 8000    // NE / NWG_BIN, exact
#define ZOFF (NN*64)  // u32-offset of the zero row in H
#define AGG_BLOCKS 1536

typedef __attribute__((ext_vector_type(4))) _Float16 f16x4;
typedef __attribute__((ext_vector_type(4))) float f32x4;

static __device__ __forceinline__ float frelu(float x){ return x > 0.f ? x : 0.f; }

// bf16 helpers (RNE pack, cheap unpack)
static __device__ __forceinline__ unsigned short f2bf(float f){
  unsigned int u = __float_as_uint(f);
  u += 0x7fffu + ((u >> 16) & 1u);
  return (unsigned short)(u >> 16);
}
static __device__ __forceinline__ float bflo(unsigned int p){ return __uint_as_float(p << 16); }
static __device__ __forceinline__ float bfhi(unsigned int p){ return __uint_as_float(p & 0xffff0000u); }

// ---------------- prep: zero colsum banks/bucketCnt/zero-row + pack W1/W2 --------
__global__ __launch_bounds__(256) void k_prep(const float* __restrict__ W1f, const float* __restrict__ W2f,
                                              unsigned long long* __restrict__ P1, unsigned long long* __restrict__ P2,
                                              float* __restrict__ colsumB, unsigned int* __restrict__ hw,
                                              int* __restrict__ bucketCnt){
  int t = threadIdx.x;
  if (blockIdx.x == 0){
    for (int i = t; i < 2048; i += 256) colsumB[i] = 0.f;   // 8 banks x 256
    if (t < 64) hw[ZOFF + t] = 0u;                          // zero sentinel row
    for (int i = t; i < NB; i += 256) bucketCnt[i] = 0;
    return;
  }
  const float* W = (blockIdx.x == 2) ? W2f : W1f;
  unsigned long long* P = (blockIdx.x == 2) ? P2 : P1;
  for (int i = 0; i < 16; i++){
    int s = t*16 + i;
    int l = s & 63, kt = (s >> 6) & 7, nt = s >> 9;
    int krow = kt*16 + ((l >> 4) << 2);
    int col = nt*16 + (l & 15);
    f16x4 v;
    #pragma unroll
    for (int j = 0; j < 4; j++) v[j] = (_Float16)W[(krow + j)*D + col];
    P[s] = __builtin_bit_cast(unsigned long long, v);
  }
}

// ---------------- build pass 1: per-WG local counting sort into own region ------
__global__ __launch_bounds__(256) void kb_sort1(const int* __restrict__ ei,
                                                int* __restrict__ wgLoc, int* __restrict__ bucketCnt,
                                                unsigned int* __restrict__ binned){
  __shared__ int hist[NBP];
  __shared__ int lofs[NBP];
  __shared__ int fill[NBP];
  __shared__ int tsum[256];
  int t = threadIdx.x, w = blockIdx.x;
  for (int i = t; i < NBP; i += 256){ hist[i] = 0; fill[i] = 0; }
  __syncthreads();

  int base = w*CHUNK;
  for (int e = base + t; e < base + CHUNK; e += 256)
    atomicAdd(&hist[ei[NE + e] >> 7], 1);
  __syncthreads();

  int b0 = t*4;
  int h0 = 0, h1 = 0, h2 = 0, h3 = 0, s = 0;
  if (b0 < NBP){
    h0 = hist[b0]; h1 = hist[b0+1]; h2 = hist[b0+2]; h3 = hist[b0+3];
    s = h0 + h1 + h2 + h3;
  }
  tsum[t] = s; __syncthreads();
  for (int off = 1; off < 256; off <<= 1){
    int u = (t >= off) ? tsum[t - off] : 0;
    __syncthreads(); tsum[t] += u; __syncthreads();
  }
  if (b0 < NBP){
    int ex = tsum[t] - s;
    lofs[b0] = ex; lofs[b0+1] = ex + h0; lofs[b0+2] = ex + h0 + h1; lofs[b0+3] = ex + h0 + h1 + h2;
  }
  __syncthreads();

  for (int i = t; i < NB + 1; i += 256) wgLoc[w*NBP + i] = lofs[i];
  for (int i = t; i < NB; i += 256) if (hist[i]) atomicAdd(&bucketCnt[i], hist[i]);

  for (int e = base + t; e < base + CHUNK; e += 256){
    int sc = ei[e], d = ei[NE + e];
    int b = d >> 7;
    int r = atomicAdd(&fill[b], 1);
    binned[base + lofs[b] + r] = ((unsigned)sc << 7) | (unsigned)(d & 127);
  }
}

// ---- pass 2: exclusive scan of bucket totals -> bucketStart[0..NB] ---------
__global__ __launch_bounds__(256) void kb_scan2(const int* __restrict__ bucketCnt, int* __restrict__ bucketStart){
  __shared__ int lds[256];
  int t = threadIdx.x;
  int v[4]; int s = 0;
  #pragma unroll
  for (int j = 0; j < 4; j++){ int i = t*4 + j; v[j] = (i < NB) ? bucketCnt[i] : 0; s += v[j]; }
  lds[t] = s; __syncthreads();
  for (int off = 1; off < 256; off <<= 1){
    int u = (t >= off) ? lds[t - off] : 0;
    __syncthreads(); lds[t] += u; __syncthreads();
  }
  int ex = lds[t] - s;
  #pragma unroll
  for (int j = 0; j < 4; j++){ int i = t*4 + j; if (i <= NB) bucketStart[i] = ex; ex += v[j]; }
}

// ---- pass 3: per-bucket node build -> cnt/rowStart/dinv/colIdx ------------------
// List layout per node: [self][edges...][ZOFF pads] padded to x8, 8 reserved extra.
__global__ __launch_bounds__(256) void kb_node2(const unsigned int* __restrict__ binned,
                                                const int* __restrict__ wgLoc,
                                                const int* __restrict__ bucketStart,
                                                int* __restrict__ cnt, int* __restrict__ rowStart,
                                                float* __restrict__ dinv, int* __restrict__ colIdx){
  __shared__ int ncnt[128], roff[128], nfill[128];
  int b = blockIdx.x, t = threadIdx.x;
  int s0 = bucketStart[b];
  int node0 = b << 7;
  int nNodes = min(128, NN - node0);
  if (t < 128){ ncnt[t] = 0; nfill[t] = 0; }
  __syncthreads();

  int fb = 0, fe = 0;
  if (t < NWG_BIN){
    fb = t*CHUNK + wgLoc[t*NBP + b];
    fe = t*CHUNK + wgLoc[t*NBP + b + 1];
    for (int e = fb; e < fe; e++)
      atomicAdd(&ncnt[binned[e] & 127], 1);
  }
  __syncthreads();
  if (t < 128) roff[t] = ncnt[t];
  __syncthreads();
  for (int off = 1; off < 128; off <<= 1){
    int u = (t >= off && t < 128) ? roff[t - off] : 0;
    __syncthreads(); if (t < 128) roff[t] += u; __syncthreads();
  }
  if (t < nNodes){
    int n = ncnt[t];
    int node = node0 + t;
    int padBase = s0 + (roff[t] - n) + 8*node;
    rowStart[node] = padBase;
    cnt[node] = n;
    dinv[node] = rsqrtf((float)(n + 1));
    colIdx[padBase] = node << 6;                 // self entry (row = node*64 u32)
    int nTot = n + 1;
    int nP = (nTot + 7) & ~7;
    for (int i = nTot; i < nP; i++) colIdx[padBase + i] = ZOFF;  // zero-row pads
  }
  __syncthreads();
  if (t < NWG_BIN){
    for (int e = fb; e < fe; e++){
      unsigned int ed = binned[e];
      int l = ed & 127;
      int r = atomicAdd(&nfill[l], 1);
      colIdx[s0 + (roff[l] - ncnt[l]) + 8*(node0 + l) + 1 + r] = (int)((ed >> 7) << 6);  // src*64
    }
  }
}

// ---------------- GEMM layer 1: H[r] = bf16( dinv[r] * (X[r] @ W) ), f32 input ----
__global__ __launch_bounds__(256) void k_gemm1(const float* __restrict__ X,
                                               const unsigned long long* __restrict__ Wpk,
                                               const float* __restrict__ dinv,
                                               unsigned short* __restrict__ H){
  int tid = threadIdx.x, lane = tid & 63;
  int row0 = blockIdx.x*64 + (tid >> 6)*16;
  int arow = row0 + (lane & 15); if (arow >= NN) arow = NN - 1;
  int kg = lane >> 4;  // 0..3

  const float4* X4 = (const float4*)X;
  f16x4 a[8];
  #pragma unroll
  for (int kt = 0; kt < 8; kt++){
    float4 xv = X4[(size_t)arow*32 + kt*4 + kg];
    f16x4 av;
    av[0] = (_Float16)xv.x; av[1] = (_Float16)xv.y;
    av[2] = (_Float16)xv.z; av[3] = (_Float16)xv.w;
    a[kt] = av;
  }

  f32x4 acc[8];
  #pragma unroll
  for (int nt = 0; nt < 8; nt++){ acc[nt][0] = 0.f; acc[nt][1] = 0.f; acc[nt][2] = 0.f; acc[nt][3] = 0.f; }

  #pragma unroll
  for (int kt = 0; kt < 8; kt++){
    #pragma unroll
    for (int nt = 0; nt < 8; nt++){
      f16x4 bfr = __builtin_bit_cast(f16x4, Wpk[(nt*8 + kt)*64 + lane]);
      acc[nt] = __builtin_amdgcn_mfma_f32_16x16x16f16(a[kt], bfr, acc[nt], 0, 0, 0);
    }
  }

  int rbase = row0 + kg*4;
  float4 dv = *(const float4*)&dinv[rbase];
  #pragma unroll
  for (int r = 0; r < 4; r++){
    int row = rbase + r;
    if (row < NN){
      float sc = (r == 0) ? dv.x : (r == 1) ? dv.y : (r == 2) ? dv.z : dv.w;
      #pragma unroll
      for (int nt = 0; nt < 8; nt++)
        H[(size_t)row*D + nt*16 + (lane & 15)] = f2bf(acc[nt][r]*sc);
    }
  }
}

// ---------------- GEMM layer 2: input = relu(gb*aggb + bb); also emits o1 (f32) ----
__global__ __launch_bounds__(256) void k_gemm2(const unsigned int* __restrict__ A,
                                               const float* __restrict__ gb, const float* __restrict__ bb,
                                               const unsigned long long* __restrict__ Wpk,
                                               const float* __restrict__ dinv,
                                               unsigned short* __restrict__ H,
                                               float* __restrict__ o1){
  int tid = threadIdx.x, lane = tid & 63;
  int row0 = blockIdx.x*64 + (tid >> 6)*16;
  int arow = row0 + (lane & 15); if (arow >= NN) arow = NN - 1;
  int kg = lane >> 4;  // 0..3

  const uint2* A2 = (const uint2*)A;
  f16x4 a[8];
  #pragma unroll
  for (int kt = 0; kt < 8; kt++){
    uint2 v = A2[(size_t)arow*32 + kt*4 + kg];
    int c0 = kt*16 + kg*4;
    float4 g = *(const float4*)&gb[c0];
    float4 bo = *(const float4*)&bb[c0];
    float r0 = frelu(bflo(v.x)*g.x + bo.x);
    float r1 = frelu(bfhi(v.x)*g.y + bo.y);
    float r2 = frelu(bflo(v.y)*g.z + bo.z);
    float r3 = frelu(bfhi(v.y)*g.w + bo.w);
    *(float4*)&o1[(size_t)arow*D + c0] = make_float4(r0, r1, r2, r3);  // fused BN+ReLU output
    f16x4 av;
    av[0] = (_Float16)r0; av[1] = (_Float16)r1; av[2] = (_Float16)r2; av[3] = (_Float16)r3;
    a[kt] = av;
  }

  f32x4 acc[8];
  #pragma unroll
  for (int nt = 0; nt < 8; nt++){ acc[nt][0] = 0.f; acc[nt][1] = 0.f; acc[nt][2] = 0.f; acc[nt][3] = 0.f; }

  #pragma unroll
  for (int kt = 0; kt < 8; kt++){
    #pragma unroll
    for (int nt = 0; nt < 8; nt++){
      f16x4 bfr = __builtin_bit_cast(f16x4, Wpk[(nt*8 + kt)*64 + lane]);
      acc[nt] = __builtin_amdgcn_mfma_f32_16x16x16f16(a[kt], bfr, acc[nt], 0, 0, 0);
    }
  }

  int rbase = row0 + kg*4;
  float4 dv = *(const float4*)&dinv[rbase];
  #pragma unroll
  for (int r = 0; r < 4; r++){
    int row = rbase + r;
    if (row < NN){
      float sc = (r == 0) ? dv.x : (r == 1) ? dv.y : (r == 2) ? dv.z : dv.w;
      #pragma unroll
      for (int nt = 0; nt < 8; nt++)
        H[(size_t)row*D + nt*16 + (lane & 15)] = f2bf(acc[nt][r]*sc);
    }
  }
}

// ---------------- aggregate v4: paired-row gathers + fused BN column sums --------
// Wave = 1 node. Lanes 0-31 gather even list entries, lanes 32-63 odd entries,
// 8 B (uint2 = 4 bf16 cols) per lane -> one VMEM fetches TWO 256 B rows.
// Self is list entry 0 (built in kb_node2); pads point at the zero row.
// Grid-stride; per-wave register colsum/colsq of rounded outputs; block-end LDS
// combine + one flush to 8-banked global colsum (bnreduce eliminated).
__global__ __launch_bounds__(256) void k_agg(const unsigned int* __restrict__ Hp,
                                             const float* __restrict__ dinv,
                                             const int* __restrict__ rowStart,
                                             const int* __restrict__ cnt,
                                             const int* __restrict__ colIdx,
                                             unsigned int* __restrict__ outb,
                                             float* __restrict__ colsumB){
  __shared__ float lsum[128], lsq[128];
  int tid = threadIdx.x;
  if (tid < 128){ lsum[tid] = 0.f; lsq[tid] = 0.f; }
  __syncthreads();

  int lane = tid & 63, l32 = lane & 31, half = lane >> 5;
  int wv = tid >> 6;
  float cs0=0.f,cs1=0.f,cs2=0.f,cs3=0.f, cq0=0.f,cq1=0.f,cq2=0.f,cq3=0.f;

  for (int g = blockIdx.x; g < NN/4; g += gridDim.x){
    int node = g*4 + wv;
    int beg = __builtin_amdgcn_readfirstlane(rowStart[node]);
    int n   = __builtin_amdgcn_readfirstlane(cnt[node]);
    int nP  = (n + 8) & ~7;            // (n+1 entries incl. self) padded to x8
    const int* cp = colIdx + beg;

    float a0=0.f, a1=0.f, a2=0.f, a3=0.f;
    for (int j = 0; j < nP; j += 8){
      int i0=cp[j  ], i1=cp[j+1], i2=cp[j+2], i3=cp[j+3];
      int i4=cp[j+4], i5=cp[j+5], i6=cp[j+6], i7=cp[j+7];
      int e0 = half ? i1 : i0;
      int e1 = half ? i3 : i2;
      int e2 = half ? i5 : i4;
      int e3 = half ? i7 : i6;
      uint2 v0 = *(const uint2*)(Hp + e0 + l32*2);
      uint2 v1 = *(const uint2*)(Hp + e1 + l32*2);
      uint2 v2 = *(const uint2*)(Hp + e2 + l32*2);
      uint2 v3 = *(const uint2*)(Hp + e3 + l32*2);
      a0 += bflo(v0.x); a1 += bfhi(v0.x); a2 += bflo(v0.y); a3 += bfhi(v0.y);
      a0 += bflo(v1.x); a1 += bfhi(v1.x); a2 += bflo(v1.y); a3 += bfhi(v1.y);
      a0 += bflo(v2.x); a1 += bfhi(v2.x); a2 += bflo(v2.y); a3 += bfhi(v2.y);
      a0 += bflo(v3.x); a1 += bfhi(v3.x); a2 += bflo(v3.y); a3 += bfhi(v3.y);
    }
    // combine even/odd halves (lane l and l+32 hold same 4 columns)
    a0 += __shfl_xor(a0, 32);
    a1 += __shfl_xor(a1, 32);
    a2 += __shfl_xor(a2, 32);
    a3 += __shfl_xor(a3, 32);

    float di = dinv[node];
    unsigned int p0 = (unsigned int)f2bf(di*a0) | ((unsigned int)f2bf(di*a1) << 16);
    unsigned int p1 = (unsigned int)f2bf(di*a2) | ((unsigned int)f2bf(di*a3) << 16);
    if (!half) ((uint2*)outb)[node*32 + l32] = make_uint2(p0, p1);

    // accumulate rounded values (both halves identical; flush uses half==0)
    float r0 = bflo(p0), r1 = bfhi(p0), r2 = bflo(p1), r3 = bfhi(p1);
    cs0 += r0; cq0 += r0*r0;
    cs1 += r1; cq1 += r1*r1;
    cs2 += r2; cq2 += r2*r2;
    cs3 += r3; cq3 += r3*r3;
  }

  if (!half){
    int c0 = l32*4;
    atomicAdd(&lsum[c0  ], cs0); atomicAdd(&lsq[c0  ], cq0);
    atomicAdd(&lsum[c0+1], cs1); atomicAdd(&lsq[c0+1], cq1);
    atomicAdd(&lsum[c0+2], cs2); atomicAdd(&lsq[c0+2], cq2);
    atomicAdd(&lsum[c0+3], cs3); atomicAdd(&lsq[c0+3], cq3);
  }
  __syncthreads();
  int bank = (blockIdx.x & 7)*256;
  if (tid < 128) atomicAdd(&colsumB[bank + tid], lsum[tid]);
  else if (tid < 256) atomicAdd(&colsumB[bank + tid], lsq[tid - 128]);
}

// mu/rstd from 8 banks -> folded gb/bb; zero banks for next layer/call
__global__ void k_bnfinal(float* __restrict__ colsumB, const float* __restrict__ gamma,
                          const float* __restrict__ beta, float* __restrict__ gb, float* __restrict__ bb){
  int c = threadIdx.x;  // 0..127
  float s = 0.f, q = 0.f;
  #pragma unroll
  for (int b = 0; b < 8; b++){
    s += colsumB[b*256 + c];
    q += colsumB[b*256 + 128 + c];
    colsumB[b*256 + c] = 0.f;
    colsumB[b*256 + 128 + c] = 0.f;
  }
  float mu = s * (1.f / NN);
  float var = q * (1.f / NN) - mu*mu;
  float g = gamma[c] * rsqrtf(var + BN_EPS);
  gb[c] = g;
  bb[c] = beta[c] - mu*g;
}

// ---------------- BN apply + ReLU: bf16 agg -> f32 out (layer 2 only) ----------
__global__ __launch_bounds__(256) void k_bnapply(const unsigned int* __restrict__ A, const float* __restrict__ gb,
                                                 const float* __restrict__ bb, float* __restrict__ out){
  int idx = blockIdx.x*256 + threadIdx.x;
  if (idx >= NN*64) return;
  unsigned int v = A[idx];
  int c2 = idx & 63;
  float2 g = ((const float2*)gb)[c2];
  float2 b = ((const float2*)bb)[c2];
  float lo = frelu(bflo(v)*g.x + b.x);
  float hi = frelu(bfhi(v)*g.y + b.y);
  ((float2*)out)[idx] = make_float2(lo, hi);
}

extern "C" void kernel_launch(void* const* d_in, const int* in_sizes, int n_in,
                              void* d_out, int out_size, void* d_ws, size_t ws_size,
                              hipStream_t stream){
  const float* x   = (const float*)d_in[0];
  const int*   ei  = (const int*)d_in[1];   // [2][NE], row0 = src, row1 = dst
  const float* W1  = (const float*)d_in[2];
  const float* g1  = (const float*)d_in[4];
  const float* be1 = (const float*)d_in[5];
  const float* W2  = (const float*)d_in[6];
  const float* g2  = (const float*)d_in[8];
  const float* be2 = (const float*)d_in[9];
  // b1/b2 cancel exactly inside BatchNorm (agg+b - mean(agg+b)) -> skipped.

  float* out = (float*)d_out;
  float* o1 = out;
  float* o2 = out + (size_t)NN*D;

  char* ws = (char*)d_ws;
  int*   cnt         = (int*)(ws + 0);           // 400000 B
  int*   rowStart    = (int*)(ws + 400384);      // 400000 B (padded starts)
  float* dinv        = (float*)(ws + 800768);    // 400000 B
  float* colsumB     = (float*)(ws + 1201152);   // 8192 B (8 banks x [128 sum | 128 sq])
  float* gb          = (float*)(ws + 1209344);   // 512 B
  float* bb          = (float*)(ws + 1209856);   // 512 B
  int*   bucketCnt   = (int*)(ws + 1210368);     // 3200 B
  int*   bucketStart = (int*)(ws + 1213568);     // 3200 B
  int*   wgLoc       = (int*)(ws + 1216768);     // 627200 B
  unsigned long long* Wpk1 = (unsigned long long*)(ws + 1844224);  // 32768 B
  unsigned long long* Wpk2 = (unsigned long long*)(ws + 1876992);  // 32768 B
  int*   colIdx      = (int*)(ws + 1909760);     // (NE + 8*NN + 256)*4 = 9601024 B
  unsigned int* binned = (unsigned int*)(ws + 11510784);  // 6.4 MB
  unsigned int* aggb = (unsigned int*)(ws + 17910784);    // 25.6 MB (bf16 agg)
  unsigned short* h  = (unsigned short*)(ws + 43510784);  // 25.6 MB + 256 B zero row
  // total ~69.1 MB of ws

  // ---- prep + write-coalesced counting-sort build ----
  k_prep    <<<3, 256, 0, stream>>>(W1, W2, Wpk1, Wpk2, colsumB, (unsigned int*)h, bucketCnt);
  kb_sort1  <<<NWG_BIN, 256, 0, stream>>>(ei, wgLoc, bucketCnt, binned);
  kb_scan2  <<<1, 256, 0, stream>>>(bucketCnt, bucketStart);
  kb_node2  <<<NB, 256, 0, stream>>>(binned, wgLoc, bucketStart, cnt, rowStart, dinv, colIdx);

  // ---- layer 1 ----
  k_gemm1   <<<(NN + 63)/64, 256, 0, stream>>>(x, Wpk1, dinv, h);
  k_agg     <<<AGG_BLOCKS, 256, 0, stream>>>((const unsigned int*)h, dinv, rowStart, cnt, colIdx, aggb, colsumB);
  k_bnfinal <<<1, 128, 0, stream>>>(colsumB, g1, be1, gb, bb);

  // ---- layer 2 (gemm reads bf16 agg, applies BN+ReLU inline, emits o1) ----
  k_gemm2   <<<(NN + 63)/64, 256, 0, stream>>>(aggb, gb, bb, Wpk2, dinv, h, o1);
  k_agg     <<<AGG_BLOCKS, 256, 0, stream>>>((const unsigned int*)h, dinv, rowStart, cnt, colIdx, aggb, colsumB);
  k_bnfinal <<<1, 128, 0, stream>>>(colsumB, g2, be2, gb, bb);
  k_bnapply <<<(NN*64 + 255)/256, 256, 0, stream>>>(aggb, gb, bb, o2);
}

// Round 9
// 283.579 us; speedup vs baseline: 1.2516x; 1.0143x over previous
//
#include <hip/hip_runtime.h>

#define NN 100000
#define NE 1600000
#define D 128
#define BN_EPS 1e-5f

#define NB 782        // ceil(NN / 128) buckets, bucket = dst >> 7
#define NBP 784       // padded bucket count (x4-per-thread scan)
#define NWG_BIN 200   // workgroups in sort pass
#define CHUNK 8000    // NE / NWG_BIN, exact
#define ZOFF (NN*64)  // u32-offset of the zero row in H
#define AGG_BLOCKS 1536

typedef __attribute__((ext_vector_type(4))) _Float16 f16x4;
typedef __attribute__((ext_vector_type(4))) float f32x4;

static __device__ __forceinline__ float frelu(float x){ return x > 0.f ? x : 0.f; }

// bf16 helpers (RNE pack, cheap unpack)
static __device__ __forceinline__ unsigned short f2bf(float f){
  unsigned int u = __float_as_uint(f);
  u += 0x7fffu + ((u >> 16) & 1u);
  return (unsigned short)(u >> 16);
}
static __device__ __forceinline__ float bflo(unsigned int p){ return __uint_as_float(p << 16); }
static __device__ __forceinline__ float bfhi(unsigned int p){ return __uint_as_float(p & 0xffff0000u); }

// ---------------- prep: zero colsum banks/bucketCnt/zero-row + pack W1/W2 --------
__global__ __launch_bounds__(256) void k_prep(const float* __restrict__ W1f, const float* __restrict__ W2f,
                                              unsigned long long* __restrict__ P1, unsigned long long* __restrict__ P2,
                                              float* __restrict__ colsumB, unsigned int* __restrict__ hw,
                                              int* __restrict__ bucketCnt){
  int t = threadIdx.x;
  if (blockIdx.x == 0){
    for (int i = t; i < 2048; i += 256) colsumB[i] = 0.f;   // 8 banks x 256
    if (t < 64) hw[ZOFF + t] = 0u;                          // zero sentinel row
    for (int i = t; i < NB; i += 256) bucketCnt[i] = 0;
    return;
  }
  const float* W = (blockIdx.x == 2) ? W2f : W1f;
  unsigned long long* P = (blockIdx.x == 2) ? P2 : P1;
  for (int i = 0; i < 16; i++){
    int s = t*16 + i;
    int l = s & 63, kt = (s >> 6) & 7, nt = s >> 9;
    int krow = kt*16 + ((l >> 4) << 2);
    int col = nt*16 + (l & 15);
    f16x4 v;
    #pragma unroll
    for (int j = 0; j < 4; j++) v[j] = (_Float16)W[(krow + j)*D + col];
    P[s] = __builtin_bit_cast(unsigned long long, v);
  }
}

// ---------------- build pass 1: per-WG local counting sort into own region ------
__global__ __launch_bounds__(256) void kb_sort1(const int* __restrict__ ei,
                                                int* __restrict__ wgLoc, int* __restrict__ bucketCnt,
                                                unsigned int* __restrict__ binned){
  __shared__ int hist[NBP];
  __shared__ int lofs[NBP];
  __shared__ int fill[NBP];
  __shared__ int tsum[256];
  int t = threadIdx.x, w = blockIdx.x;
  for (int i = t; i < NBP; i += 256){ hist[i] = 0; fill[i] = 0; }
  __syncthreads();

  int base = w*CHUNK;
  for (int e = base + t; e < base + CHUNK; e += 256)
    atomicAdd(&hist[ei[NE + e] >> 7], 1);
  __syncthreads();

  int b0 = t*4;
  int h0 = 0, h1 = 0, h2 = 0, h3 = 0, s = 0;
  if (b0 < NBP){
    h0 = hist[b0]; h1 = hist[b0+1]; h2 = hist[b0+2]; h3 = hist[b0+3];
    s = h0 + h1 + h2 + h3;
  }
  tsum[t] = s; __syncthreads();
  for (int off = 1; off < 256; off <<= 1){
    int u = (t >= off) ? tsum[t - off] : 0;
    __syncthreads(); tsum[t] += u; __syncthreads();
  }
  if (b0 < NBP){
    int ex = tsum[t] - s;
    lofs[b0] = ex; lofs[b0+1] = ex + h0; lofs[b0+2] = ex + h0 + h1; lofs[b0+3] = ex + h0 + h1 + h2;
  }
  __syncthreads();

  for (int i = t; i < NB + 1; i += 256) wgLoc[w*NBP + i] = lofs[i];
  for (int i = t; i < NB; i += 256) if (hist[i]) atomicAdd(&bucketCnt[i], hist[i]);

  for (int e = base + t; e < base + CHUNK; e += 256){
    int sc = ei[e], d = ei[NE + e];
    int b = d >> 7;
    int r = atomicAdd(&fill[b], 1);
    binned[base + lofs[b] + r] = ((unsigned)sc << 7) | (unsigned)(d & 127);
  }
}

// ---- pass 2: per-bucket node build -> cnt/rowStart/dinv/colIdx ------------------
// bucketStart computed in-block: s0 = sum_{i<b} bucketCnt[i] (strided read + reduce).
// List layout per node: [self][edges...][ZOFF pads] padded to x8.
__global__ __launch_bounds__(256) void kb_node2(const unsigned int* __restrict__ binned,
                                                const int* __restrict__ wgLoc,
                                                const int* __restrict__ bucketCnt,
                                                int* __restrict__ cnt, int* __restrict__ rowStart,
                                                float* __restrict__ dinv, int* __restrict__ colIdx){
  __shared__ int ncnt[128], roff[128], nfill[128];
  __shared__ int psum[256];
  int b = blockIdx.x, t = threadIdx.x;

  // in-block exclusive prefix: s0 = sum of bucketCnt[0..b)
  int acc = 0;
  for (int i = t; i < b; i += 256) acc += bucketCnt[i];
  psum[t] = acc;
  if (t < 128){ ncnt[t] = 0; nfill[t] = 0; }
  __syncthreads();
  for (int off = 128; off > 0; off >>= 1){
    if (t < off) psum[t] += psum[t + off];
    __syncthreads();
  }
  int s0 = psum[0];

  int node0 = b << 7;
  int nNodes = min(128, NN - node0);

  int fb = 0, fe = 0;
  if (t < NWG_BIN){
    fb = t*CHUNK + wgLoc[t*NBP + b];
    fe = t*CHUNK + wgLoc[t*NBP + b + 1];
    for (int e = fb; e < fe; e++)
      atomicAdd(&ncnt[binned[e] & 127], 1);
  }
  __syncthreads();
  if (t < 128) roff[t] = ncnt[t];
  __syncthreads();
  for (int off = 1; off < 128; off <<= 1){
    int u = (t >= off && t < 128) ? roff[t - off] : 0;
    __syncthreads(); if (t < 128) roff[t] += u; __syncthreads();
  }
  if (t < nNodes){
    int n = ncnt[t];
    int node = node0 + t;
    int padBase = s0 + (roff[t] - n) + 8*node;
    rowStart[node] = padBase;
    cnt[node] = n;
    dinv[node] = rsqrtf((float)(n + 1));
    colIdx[padBase] = node << 6;                 // self entry (row = node*64 u32)
    int nTot = n + 1;
    int nP = (nTot + 7) & ~7;
    for (int i = nTot; i < nP; i++) colIdx[padBase + i] = ZOFF;  // zero-row pads
  }
  __syncthreads();
  if (t < NWG_BIN){
    for (int e = fb; e < fe; e++){
      unsigned int ed = binned[e];
      int l = ed & 127;
      int r = atomicAdd(&nfill[l], 1);
      colIdx[s0 + (roff[l] - ncnt[l]) + 8*(node0 + l) + 1 + r] = (int)((ed >> 7) << 6);  // src*64
    }
  }
}

// ---------------- GEMM layer 1: H[r] = bf16( dinv[r] * (X[r] @ W) ), f32 input ----
__global__ __launch_bounds__(256) void k_gemm1(const float* __restrict__ X,
                                               const unsigned long long* __restrict__ Wpk,
                                               const float* __restrict__ dinv,
                                               unsigned short* __restrict__ H){
  int tid = threadIdx.x, lane = tid & 63;
  int row0 = blockIdx.x*64 + (tid >> 6)*16;
  int arow = row0 + (lane & 15); if (arow >= NN) arow = NN - 1;
  int kg = lane >> 4;  // 0..3

  const float4* X4 = (const float4*)X;
  f16x4 a[8];
  #pragma unroll
  for (int kt = 0; kt < 8; kt++){
    float4 xv = X4[(size_t)arow*32 + kt*4 + kg];
    f16x4 av;
    av[0] = (_Float16)xv.x; av[1] = (_Float16)xv.y;
    av[2] = (_Float16)xv.z; av[3] = (_Float16)xv.w;
    a[kt] = av;
  }

  f32x4 acc[8];
  #pragma unroll
  for (int nt = 0; nt < 8; nt++){ acc[nt][0] = 0.f; acc[nt][1] = 0.f; acc[nt][2] = 0.f; acc[nt][3] = 0.f; }

  #pragma unroll
  for (int kt = 0; kt < 8; kt++){
    #pragma unroll
    for (int nt = 0; nt < 8; nt++){
      f16x4 bfr = __builtin_bit_cast(f16x4, Wpk[(nt*8 + kt)*64 + lane]);
      acc[nt] = __builtin_amdgcn_mfma_f32_16x16x16f16(a[kt], bfr, acc[nt], 0, 0, 0);
    }
  }

  int rbase = row0 + kg*4;
  float4 dv = *(const float4*)&dinv[rbase];
  #pragma unroll
  for (int r = 0; r < 4; r++){
    int row = rbase + r;
    if (row < NN){
      float sc = (r == 0) ? dv.x : (r == 1) ? dv.y : (r == 2) ? dv.z : dv.w;
      #pragma unroll
      for (int nt = 0; nt < 8; nt++)
        H[(size_t)row*D + nt*16 + (lane & 15)] = f2bf(acc[nt][r]*sc);
    }
  }
}

// ---------------- GEMM layer 2: input = relu(gb*aggb + bb); also emits o1 (f32) ----
__global__ __launch_bounds__(256) void k_gemm2(const unsigned int* __restrict__ A,
                                               const float* __restrict__ gb, const float* __restrict__ bb,
                                               const unsigned long long* __restrict__ Wpk,
                                               const float* __restrict__ dinv,
                                               unsigned short* __restrict__ H,
                                               float* __restrict__ o1){
  int tid = threadIdx.x, lane = tid & 63;
  int row0 = blockIdx.x*64 + (tid >> 6)*16;
  int arow = row0 + (lane & 15); if (arow >= NN) arow = NN - 1;
  int kg = lane >> 4;  // 0..3

  const uint2* A2 = (const uint2*)A;
  f16x4 a[8];
  #pragma unroll
  for (int kt = 0; kt < 8; kt++){
    uint2 v = A2[(size_t)arow*32 + kt*4 + kg];
    int c0 = kt*16 + kg*4;
    float4 g = *(const float4*)&gb[c0];
    float4 bo = *(const float4*)&bb[c0];
    float r0 = frelu(bflo(v.x)*g.x + bo.x);
    float r1 = frelu(bfhi(v.x)*g.y + bo.y);
    float r2 = frelu(bflo(v.y)*g.z + bo.z);
    float r3 = frelu(bfhi(v.y)*g.w + bo.w);
    *(float4*)&o1[(size_t)arow*D + c0] = make_float4(r0, r1, r2, r3);  // fused BN+ReLU output
    f16x4 av;
    av[0] = (_Float16)r0; av[1] = (_Float16)r1; av[2] = (_Float16)r2; av[3] = (_Float16)r3;
    a[kt] = av;
  }

  f32x4 acc[8];
  #pragma unroll
  for (int nt = 0; nt < 8; nt++){ acc[nt][0] = 0.f; acc[nt][1] = 0.f; acc[nt][2] = 0.f; acc[nt][3] = 0.f; }

  #pragma unroll
  for (int kt = 0; kt < 8; kt++){
    #pragma unroll
    for (int nt = 0; nt < 8; nt++){
      f16x4 bfr = __builtin_bit_cast(f16x4, Wpk[(nt*8 + kt)*64 + lane]);
      acc[nt] = __builtin_amdgcn_mfma_f32_16x16x16f16(a[kt], bfr, acc[nt], 0, 0, 0);
    }
  }

  int rbase = row0 + kg*4;
  float4 dv = *(const float4*)&dinv[rbase];
  #pragma unroll
  for (int r = 0; r < 4; r++){
    int row = rbase + r;
    if (row < NN){
      float sc = (r == 0) ? dv.x : (r == 1) ? dv.y : (r == 2) ? dv.z : dv.w;
      #pragma unroll
      for (int nt = 0; nt < 8; nt++)
        H[(size_t)row*D + nt*16 + (lane & 15)] = f2bf(acc[nt][r]*sc);
    }
  }
}

// ---------------- aggregate v5: R6 gather shape + fused BN column sums -----------
// Wave = 1 node; lane owns columns (2*lane, 2*lane+1) as one u32. Scalar CSR walk
// (readfirstlane), unroll-8 with 8 independent accumulator pairs. Self is list
// entry 0; pads point at the zero row. Grid-stride; per-lane register colsum/colsq
// of rounded outputs; block-end LDS combine + one flush to 8-banked global colsum.
__global__ __launch_bounds__(256) void k_agg(const unsigned int* __restrict__ Hp,
                                             const float* __restrict__ dinv,
                                             const int* __restrict__ rowStart,
                                             const int* __restrict__ cnt,
                                             const int* __restrict__ colIdx,
                                             unsigned int* __restrict__ outb,
                                             float* __restrict__ colsumB){
  __shared__ float lsum[128], lsq[128];
  int tid = threadIdx.x;
  if (tid < 128){ lsum[tid] = 0.f; lsq[tid] = 0.f; }
  __syncthreads();

  int lane = tid & 63, wv = tid >> 6;
  float cs0 = 0.f, cs1 = 0.f, cq0 = 0.f, cq1 = 0.f;

  for (int g = blockIdx.x; g < NN/4; g += gridDim.x){
    int node = g*4 + wv;
    int beg = __builtin_amdgcn_readfirstlane(rowStart[node]);
    int n   = __builtin_amdgcn_readfirstlane(cnt[node]);
    int nP  = (n + 8) & ~7;            // (n+1 entries incl. self) padded to x8
    const int* cp = colIdx + beg;

    float2 a0 = make_float2(0.f, 0.f), a1 = a0, a2 = a0, a3 = a0;
    float2 a4 = a0, a5 = a0, a6 = a0, a7 = a0;
    for (int j = 0; j < nP; j += 8){
      int i0 = cp[j  ], i1 = cp[j+1], i2 = cp[j+2], i3 = cp[j+3];
      int i4 = cp[j+4], i5 = cp[j+5], i6 = cp[j+6], i7 = cp[j+7];
      unsigned int v0 = Hp[i0 + lane];
      unsigned int v1 = Hp[i1 + lane];
      unsigned int v2 = Hp[i2 + lane];
      unsigned int v3 = Hp[i3 + lane];
      unsigned int v4 = Hp[i4 + lane];
      unsigned int v5 = Hp[i5 + lane];
      unsigned int v6 = Hp[i6 + lane];
      unsigned int v7 = Hp[i7 + lane];
      a0.x += bflo(v0); a0.y += bfhi(v0);
      a1.x += bflo(v1); a1.y += bfhi(v1);
      a2.x += bflo(v2); a2.y += bfhi(v2);
      a3.x += bflo(v3); a3.y += bfhi(v3);
      a4.x += bflo(v4); a4.y += bfhi(v4);
      a5.x += bflo(v5); a5.y += bfhi(v5);
      a6.x += bflo(v6); a6.y += bfhi(v6);
      a7.x += bflo(v7); a7.y += bfhi(v7);
    }

    float sx = ((a0.x + a1.x) + (a2.x + a3.x)) + ((a4.x + a5.x) + (a6.x + a7.x));
    float sy = ((a0.y + a1.y) + (a2.y + a3.y)) + ((a4.y + a5.y) + (a6.y + a7.y));
    float di = dinv[node];
    unsigned int pk = (unsigned int)f2bf(di*sx) | ((unsigned int)f2bf(di*sy) << 16);
    outb[node*64 + lane] = pk;

    float r0 = bflo(pk), r1 = bfhi(pk);
    cs0 += r0; cq0 += r0*r0;
    cs1 += r1; cq1 += r1*r1;
  }

  atomicAdd(&lsum[lane*2    ], cs0); atomicAdd(&lsq[lane*2    ], cq0);
  atomicAdd(&lsum[lane*2 + 1], cs1); atomicAdd(&lsq[lane*2 + 1], cq1);
  __syncthreads();
  int bank = (blockIdx.x & 7)*256;
  if (tid < 128) atomicAdd(&colsumB[bank + tid], lsum[tid]);
  else if (tid < 256) atomicAdd(&colsumB[bank + tid], lsq[tid - 128]);
}

// mu/rstd from 8 banks -> folded gb/bb; zero banks for next layer/call
__global__ void k_bnfinal(float* __restrict__ colsumB, const float* __restrict__ gamma,
                          const float* __restrict__ beta, float* __restrict__ gb, float* __restrict__ bb){
  int c = threadIdx.x;  // 0..127
  float s = 0.f, q = 0.f;
  #pragma unroll
  for (int b = 0; b < 8; b++){
    s += colsumB[b*256 + c];
    q += colsumB[b*256 + 128 + c];
    colsumB[b*256 + c] = 0.f;
    colsumB[b*256 + 128 + c] = 0.f;
  }
  float mu = s * (1.f / NN);
  float var = q * (1.f / NN) - mu*mu;
  float g = gamma[c] * rsqrtf(var + BN_EPS);
  gb[c] = g;
  bb[c] = beta[c] - mu*g;
}

// ---------------- BN apply + ReLU: bf16 agg -> f32 out (layer 2 only) ----------
__global__ __launch_bounds__(256) void k_bnapply(const unsigned int* __restrict__ A, const float* __restrict__ gb,
                                                 const float* __restrict__ bb, float* __restrict__ out){
  int idx = blockIdx.x*256 + threadIdx.x;
  if (idx >= NN*64) return;
  unsigned int v = A[idx];
  int c2 = idx & 63;
  float2 g = ((const float2*)gb)[c2];
  float2 b = ((const float2*)bb)[c2];
  float lo = frelu(bflo(v)*g.x + b.x);
  float hi = frelu(bfhi(v)*g.y + b.y);
  ((float2*)out)[idx] = make_float2(lo, hi);
}

extern "C" void kernel_launch(void* const* d_in, const int* in_sizes, int n_in,
                              void* d_out, int out_size, void* d_ws, size_t ws_size,
                              hipStream_t stream){
  const float* x   = (const float*)d_in[0];
  const int*   ei  = (const int*)d_in[1];   // [2][NE], row0 = src, row1 = dst
  const float* W1  = (const float*)d_in[2];
  const float* g1  = (const float*)d_in[4];
  const float* be1 = (const float*)d_in[5];
  const float* W2  = (const float*)d_in[6];
  const float* g2  = (const float*)d_in[8];
  const float* be2 = (const float*)d_in[9];
  // b1/b2 cancel exactly inside BatchNorm (agg+b - mean(agg+b)) -> skipped.

  float* out = (float*)d_out;
  float* o1 = out;
  float* o2 = out + (size_t)NN*D;

  char* ws = (char*)d_ws;
  int*   cnt         = (int*)(ws + 0);           // 400000 B
  int*   rowStart    = (int*)(ws + 400384);      // 400000 B (padded starts)
  float* dinv        = (float*)(ws + 800768);    // 400000 B
  float* colsumB     = (float*)(ws + 1201152);   // 8192 B (8 banks x [128 sum | 128 sq])
  float* gb          = (float*)(ws + 1209344);   // 512 B
  float* bb          = (float*)(ws + 1209856);   // 512 B
  int*   bucketCnt   = (int*)(ws + 1210368);     // 3200 B
  int*   wgLoc       = (int*)(ws + 1213568);     // 627200 B
  unsigned long long* Wpk1 = (unsigned long long*)(ws + 1841024);  // 32768 B
  unsigned long long* Wpk2 = (unsigned long long*)(ws + 1873792);  // 32768 B
  int*   colIdx      = (int*)(ws + 1906560);     // (NE + 8*NN + 256)*4 = 9601024 B
  unsigned int* binned = (unsigned int*)(ws + 11507584);  // 6.4 MB
  unsigned int* aggb = (unsigned int*)(ws + 17907584);    // 25.6 MB (bf16 agg)
  unsigned short* h  = (unsigned short*)(ws + 43507584);  // 25.6 MB + 256 B zero row
  // total ~69.1 MB of ws

  // ---- prep + write-coalesced counting-sort build (scan fused into node build) ----
  k_prep    <<<3, 256, 0, stream>>>(W1, W2, Wpk1, Wpk2, colsumB, (unsigned int*)h, bucketCnt);
  kb_sort1  <<<NWG_BIN, 256, 0, stream>>>(ei, wgLoc, bucketCnt, binned);
  kb_node2  <<<NB, 256, 0, stream>>>(binned, wgLoc, bucketCnt, cnt, rowStart, dinv, colIdx);

  // ---- layer 1 ----
  k_gemm1   <<<(NN + 63)/64, 256, 0, stream>>>(x, Wpk1, dinv, h);
  k_agg     <<<AGG_BLOCKS, 256, 0, stream>>>((const unsigned int*)h, dinv, rowStart, cnt, colIdx, aggb, colsumB);
  k_bnfinal <<<1, 128, 0, stream>>>(colsumB, g1, be1, gb, bb);

  // ---- layer 2 (gemm reads bf16 agg, applies BN+ReLU inline, emits o1) ----
  k_gemm2   <<<(NN + 63)/64, 256, 0, stream>>>(aggb, gb, bb, Wpk2, dinv, h, o1);
  k_agg     <<<AGG_BLOCKS, 256, 0, stream>>>((const unsigned int*)h, dinv, rowStart, cnt, colIdx, aggb, colsumB);
  k_bnfinal <<<1, 128, 0, stream>>>(colsumB, g2, be2, gb, bb);
  k_bnapply <<<(NN*64 + 255)/256, 256, 0, stream>>>(aggb, gb, bb, o2);
}

// Round 10
// 265.360 us; speedup vs baseline: 1.3376x; 1.0687x over previous
//
#include <hip/hip_runtime.h>

#define NN 100000
#define NE 1600000
#define D 128
#define BN_EPS 1e-5f

#define NB 782        // ceil(NN / 128) buckets, bucket = dst >> 7
#define NBP 784       // padded bucket count
#define NWG_BIN 200   // workgroups in sort pass
#define CHUNK 8000    // NE / NWG_BIN, exact
#define ZOFF (NN*64)  // u32-offset of the zero row in H
#define AGG_BLOCKS 2048

typedef __attribute__((ext_vector_type(4))) _Float16 f16x4;
typedef __attribute__((ext_vector_type(4))) float f32x4;

static __device__ __forceinline__ float frelu(float x){ return x > 0.f ? x : 0.f; }

// bf16 helpers (RNE pack, cheap unpack)
static __device__ __forceinline__ unsigned short f2bf(float f){
  unsigned int u = __float_as_uint(f);
  u += 0x7fffu + ((u >> 16) & 1u);
  return (unsigned short)(u >> 16);
}
static __device__ __forceinline__ float bflo(unsigned int p){ return __uint_as_float(p << 16); }
static __device__ __forceinline__ float bfhi(unsigned int p){ return __uint_as_float(p & 0xffff0000u); }

// ---------------- sort + prep fused: blocks 0..199 sort, 200 zero, 201/202 pack W ----
__global__ __launch_bounds__(256) void k_sortprep(const int* __restrict__ ei,
                                                  int* __restrict__ wgLoc, unsigned int* __restrict__ binned,
                                                  const float* __restrict__ W1f, const float* __restrict__ W2f,
                                                  unsigned long long* __restrict__ P1, unsigned long long* __restrict__ P2,
                                                  float* __restrict__ colsumB, unsigned int* __restrict__ hw){
  __shared__ int hist[NBP];
  __shared__ int lofs[NBP];
  __shared__ int fill[NBP];
  __shared__ int tsum[256];
  int t = threadIdx.x, w = blockIdx.x;

  if (w >= NWG_BIN){
    if (w == NWG_BIN){
      for (int i = t; i < 4096; i += 256) colsumB[i] = 0.f;  // 2 regions x 8 banks x 256
      if (t < 64) hw[ZOFF + t] = 0u;                          // zero sentinel row
    } else {
      const float* W = (w == NWG_BIN + 2) ? W2f : W1f;
      unsigned long long* P = (w == NWG_BIN + 2) ? P2 : P1;
      for (int i = 0; i < 16; i++){
        int s = t*16 + i;
        int l = s & 63, kt = (s >> 6) & 7, nt = s >> 9;
        int krow = kt*16 + ((l >> 4) << 2);
        int col = nt*16 + (l & 15);
        f16x4 v;
        #pragma unroll
        for (int j = 0; j < 4; j++) v[j] = (_Float16)W[(krow + j)*D + col];
        P[s] = __builtin_bit_cast(unsigned long long, v);
      }
    }
    return;
  }

  // ---- per-WG local counting sort into own region ----
  for (int i = t; i < NBP; i += 256){ hist[i] = 0; fill[i] = 0; }
  __syncthreads();

  int base = w*CHUNK;
  for (int e = base + t; e < base + CHUNK; e += 256)
    atomicAdd(&hist[ei[NE + e] >> 7], 1);
  __syncthreads();

  int b0 = t*4;
  int h0 = 0, h1 = 0, h2 = 0, h3 = 0, s = 0;
  if (b0 < NBP){
    h0 = hist[b0]; h1 = hist[b0+1]; h2 = hist[b0+2]; h3 = hist[b0+3];
    s = h0 + h1 + h2 + h3;
  }
  tsum[t] = s; __syncthreads();
  for (int off = 1; off < 256; off <<= 1){
    int u = (t >= off) ? tsum[t - off] : 0;
    __syncthreads(); tsum[t] += u; __syncthreads();
  }
  if (b0 < NBP){
    int ex = tsum[t] - s;
    lofs[b0] = ex; lofs[b0+1] = ex + h0; lofs[b0+2] = ex + h0 + h1; lofs[b0+3] = ex + h0 + h1 + h2;
  }
  __syncthreads();

  for (int i = t; i < NB + 1; i += 256) wgLoc[w*NBP + i] = lofs[i];

  for (int e = base + t; e < base + CHUNK; e += 256){
    int sc = ei[e], d = ei[NE + e];
    int b = d >> 7;
    int r = atomicAdd(&fill[b], 1);
    binned[base + lofs[b] + r] = ((unsigned)sc << 7) | (unsigned)(d & 127);
  }
}

// ---- per-bucket node build -> cnt/rowStart/dinv/colIdx ---------------------------
// s0 = sum_w wgLoc[w][b]  (each wgLoc row is a per-WG exclusive scan => column sum
// is the global bucket prefix). List per node: [self][edges...][ZOFF pads], x8.
__global__ __launch_bounds__(256) void kb_node2(const unsigned int* __restrict__ binned,
                                                const int* __restrict__ wgLoc,
                                                int* __restrict__ cnt, int* __restrict__ rowStart,
                                                float* __restrict__ dinv, int* __restrict__ colIdx){
  __shared__ int ncnt[128], roff[128], nfill[128];
  __shared__ int psum[256];
  int b = blockIdx.x, t = threadIdx.x;

  psum[t] = (t < NWG_BIN) ? wgLoc[t*NBP + b] : 0;
  if (t < 128){ ncnt[t] = 0; nfill[t] = 0; }
  __syncthreads();
  for (int off = 128; off > 0; off >>= 1){
    if (t < off) psum[t] += psum[t + off];
    __syncthreads();
  }
  int s0 = psum[0];

  int node0 = b << 7;
  int nNodes = min(128, NN - node0);

  int fb = 0, fe = 0;
  if (t < NWG_BIN){
    fb = t*CHUNK + wgLoc[t*NBP + b];
    fe = t*CHUNK + wgLoc[t*NBP + b + 1];
    for (int e = fb; e < fe; e++)
      atomicAdd(&ncnt[binned[e] & 127], 1);
  }
  __syncthreads();
  if (t < 128) roff[t] = ncnt[t];
  __syncthreads();
  for (int off = 1; off < 128; off <<= 1){
    int u = (t >= off && t < 128) ? roff[t - off] : 0;
    __syncthreads(); if (t < 128) roff[t] += u; __syncthreads();
  }
  if (t < nNodes){
    int n = ncnt[t];
    int node = node0 + t;
    int padBase = s0 + (roff[t] - n) + 8*node;
    rowStart[node] = padBase;
    cnt[node] = n;
    dinv[node] = rsqrtf((float)(n + 1));
    colIdx[padBase] = node << 6;                 // self entry
    int nTot = n + 1;
    int nP = (nTot + 7) & ~7;
    for (int i = nTot; i < nP; i++) colIdx[padBase + i] = ZOFF;  // zero-row pads
  }
  __syncthreads();
  if (t < NWG_BIN){
    for (int e = fb; e < fe; e++){
      unsigned int ed = binned[e];
      int l = ed & 127;
      int r = atomicAdd(&nfill[l], 1);
      colIdx[s0 + (roff[l] - ncnt[l]) + 8*(node0 + l) + 1 + r] = (int)((ed >> 7) << 6);  // src*64
    }
  }
}

// ---------------- GEMM layer 1: H[r] = bf16( dinv[r] * (X[r] @ W) ), f32 input ----
__global__ __launch_bounds__(256) void k_gemm1(const float* __restrict__ X,
                                               const unsigned long long* __restrict__ Wpk,
                                               const float* __restrict__ dinv,
                                               unsigned short* __restrict__ H){
  int tid = threadIdx.x, lane = tid & 63;
  int row0 = blockIdx.x*64 + (tid >> 6)*16;
  int arow = row0 + (lane & 15); if (arow >= NN) arow = NN - 1;
  int kg = lane >> 4;  // 0..3

  const float4* X4 = (const float4*)X;
  f16x4 a[8];
  #pragma unroll
  for (int kt = 0; kt < 8; kt++){
    float4 xv = X4[(size_t)arow*32 + kt*4 + kg];
    f16x4 av;
    av[0] = (_Float16)xv.x; av[1] = (_Float16)xv.y;
    av[2] = (_Float16)xv.z; av[3] = (_Float16)xv.w;
    a[kt] = av;
  }

  f32x4 acc[8];
  #pragma unroll
  for (int nt = 0; nt < 8; nt++){ acc[nt][0] = 0.f; acc[nt][1] = 0.f; acc[nt][2] = 0.f; acc[nt][3] = 0.f; }

  #pragma unroll
  for (int kt = 0; kt < 8; kt++){
    #pragma unroll
    for (int nt = 0; nt < 8; nt++){
      f16x4 bfr = __builtin_bit_cast(f16x4, Wpk[(nt*8 + kt)*64 + lane]);
      acc[nt] = __builtin_amdgcn_mfma_f32_16x16x16f16(a[kt], bfr, acc[nt], 0, 0, 0);
    }
  }

  int rbase = row0 + kg*4;
  float4 dv = *(const float4*)&dinv[rbase];
  #pragma unroll
  for (int r = 0; r < 4; r++){
    int row = rbase + r;
    if (row < NN){
      float sc = (r == 0) ? dv.x : (r == 1) ? dv.y : (r == 2) ? dv.z : dv.w;
      #pragma unroll
      for (int nt = 0; nt < 8; nt++)
        H[(size_t)row*D + nt*16 + (lane & 15)] = f2bf(acc[nt][r]*sc);
    }
  }
}

// ---------------- GEMM layer 2: gb/bb computed inline from colsum region ---------
__global__ __launch_bounds__(256) void k_gemm2(const unsigned int* __restrict__ A,
                                               const float* __restrict__ colsum,
                                               const float* __restrict__ gamma, const float* __restrict__ beta,
                                               const unsigned long long* __restrict__ Wpk,
                                               const float* __restrict__ dinv,
                                               unsigned short* __restrict__ H,
                                               float* __restrict__ o1){
  __shared__ float gbL[128], bbL[128];
  int tid = threadIdx.x, lane = tid & 63;
  if (tid < 128){
    float s = 0.f, q = 0.f;
    #pragma unroll
    for (int k = 0; k < 8; k++){ s += colsum[k*256 + tid]; q += colsum[k*256 + 128 + tid]; }
    float mu = s * (1.f / NN);
    float var = q * (1.f / NN) - mu*mu;
    float g = gamma[tid] * rsqrtf(var + BN_EPS);
    gbL[tid] = g;
    bbL[tid] = beta[tid] - mu*g;
  }
  __syncthreads();

  int row0 = blockIdx.x*64 + (tid >> 6)*16;
  int arow = row0 + (lane & 15); if (arow >= NN) arow = NN - 1;
  int kg = lane >> 4;  // 0..3

  const uint2* A2 = (const uint2*)A;
  f16x4 a[8];
  #pragma unroll
  for (int kt = 0; kt < 8; kt++){
    uint2 v = A2[(size_t)arow*32 + kt*4 + kg];
    int c0 = kt*16 + kg*4;
    float4 g = *(const float4*)&gbL[c0];
    float4 bo = *(const float4*)&bbL[c0];
    float r0 = frelu(bflo(v.x)*g.x + bo.x);
    float r1 = frelu(bfhi(v.x)*g.y + bo.y);
    float r2 = frelu(bflo(v.y)*g.z + bo.z);
    float r3 = frelu(bfhi(v.y)*g.w + bo.w);
    *(float4*)&o1[(size_t)arow*D + c0] = make_float4(r0, r1, r2, r3);  // fused BN+ReLU output
    f16x4 av;
    av[0] = (_Float16)r0; av[1] = (_Float16)r1; av[2] = (_Float16)r2; av[3] = (_Float16)r3;
    a[kt] = av;
  }

  f32x4 acc[8];
  #pragma unroll
  for (int nt = 0; nt < 8; nt++){ acc[nt][0] = 0.f; acc[nt][1] = 0.f; acc[nt][2] = 0.f; acc[nt][3] = 0.f; }

  #pragma unroll
  for (int kt = 0; kt < 8; kt++){
    #pragma unroll
    for (int nt = 0; nt < 8; nt++){
      f16x4 bfr = __builtin_bit_cast(f16x4, Wpk[(nt*8 + kt)*64 + lane]);
      acc[nt] = __builtin_amdgcn_mfma_f32_16x16x16f16(a[kt], bfr, acc[nt], 0, 0, 0);
    }
  }

  int rbase = row0 + kg*4;
  float4 dv = *(const float4*)&dinv[rbase];
  #pragma unroll
  for (int r = 0; r < 4; r++){
    int row = rbase + r;
    if (row < NN){
      float sc = (r == 0) ? dv.x : (r == 1) ? dv.y : (r == 2) ? dv.z : dv.w;
      #pragma unroll
      for (int nt = 0; nt < 8; nt++)
        H[(size_t)row*D + nt*16 + (lane & 15)] = f2bf(acc[nt][r]*sc);
    }
  }
}

// ---------------- aggregate: R6 gather shape + fused BN column sums --------------
__global__ __launch_bounds__(256) void k_agg(const unsigned int* __restrict__ Hp,
                                             const float* __restrict__ dinv,
                                             const int* __restrict__ rowStart,
                                             const int* __restrict__ cnt,
                                             const int* __restrict__ colIdx,
                                             unsigned int* __restrict__ outb,
                                             float* __restrict__ colsumR){
  __shared__ float lsum[128], lsq[128];
  int tid = threadIdx.x;
  if (tid < 128){ lsum[tid] = 0.f; lsq[tid] = 0.f; }
  __syncthreads();

  int lane = tid & 63, wv = tid >> 6;
  float cs0 = 0.f, cs1 = 0.f, cq0 = 0.f, cq1 = 0.f;

  for (int g = blockIdx.x; g < NN/4; g += gridDim.x){
    int node = g*4 + wv;
    int beg = __builtin_amdgcn_readfirstlane(rowStart[node]);
    int n   = __builtin_amdgcn_readfirstlane(cnt[node]);
    int nP  = (n + 8) & ~7;            // (n+1 entries incl. self) padded to x8
    const int* cp = colIdx + beg;

    float2 a0 = make_float2(0.f, 0.f), a1 = a0, a2 = a0, a3 = a0;
    float2 a4 = a0, a5 = a0, a6 = a0, a7 = a0;
    for (int j = 0; j < nP; j += 8){
      int i0 = cp[j  ], i1 = cp[j+1], i2 = cp[j+2], i3 = cp[j+3];
      int i4 = cp[j+4], i5 = cp[j+5], i6 = cp[j+6], i7 = cp[j+7];
      unsigned int v0 = Hp[i0 + lane];
      unsigned int v1 = Hp[i1 + lane];
      unsigned int v2 = Hp[i2 + lane];
      unsigned int v3 = Hp[i3 + lane];
      unsigned int v4 = Hp[i4 + lane];
      unsigned int v5 = Hp[i5 + lane];
      unsigned int v6 = Hp[i6 + lane];
      unsigned int v7 = Hp[i7 + lane];
      a0.x += bflo(v0); a0.y += bfhi(v0);
      a1.x += bflo(v1); a1.y += bfhi(v1);
      a2.x += bflo(v2); a2.y += bfhi(v2);
      a3.x += bflo(v3); a3.y += bfhi(v3);
      a4.x += bflo(v4); a4.y += bfhi(v4);
      a5.x += bflo(v5); a5.y += bfhi(v5);
      a6.x += bflo(v6); a6.y += bfhi(v6);
      a7.x += bflo(v7); a7.y += bfhi(v7);
    }

    float sx = ((a0.x + a1.x) + (a2.x + a3.x)) + ((a4.x + a5.x) + (a6.x + a7.x));
    float sy = ((a0.y + a1.y) + (a2.y + a3.y)) + ((a4.y + a5.y) + (a6.y + a7.y));
    float di = dinv[node];
    unsigned int pk = (unsigned int)f2bf(di*sx) | ((unsigned int)f2bf(di*sy) << 16);
    outb[node*64 + lane] = pk;

    float r0 = bflo(pk), r1 = bfhi(pk);
    cs0 += r0; cq0 += r0*r0;
    cs1 += r1; cq1 += r1*r1;
  }

  atomicAdd(&lsum[lane*2    ], cs0); atomicAdd(&lsq[lane*2    ], cq0);
  atomicAdd(&lsum[lane*2 + 1], cs1); atomicAdd(&lsq[lane*2 + 1], cq1);
  __syncthreads();
  int bank = (blockIdx.x & 7)*256;
  if (tid < 128) atomicAdd(&colsumR[bank + tid], lsum[tid]);
  else if (tid < 256) atomicAdd(&colsumR[bank + tid], lsq[tid - 128]);
}

// ---------------- BN apply + ReLU (layer 2): gb/bb inline, grid-stride -----------
__global__ __launch_bounds__(256) void k_bnapply(const unsigned int* __restrict__ A,
                                                 const float* __restrict__ colsum,
                                                 const float* __restrict__ gamma, const float* __restrict__ beta,
                                                 float* __restrict__ out){
  __shared__ float gbL[128], bbL[128];
  int tid = threadIdx.x;
  if (tid < 128){
    float s = 0.f, q = 0.f;
    #pragma unroll
    for (int k = 0; k < 8; k++){ s += colsum[k*256 + tid]; q += colsum[k*256 + 128 + tid]; }
    float mu = s * (1.f / NN);
    float var = q * (1.f / NN) - mu*mu;
    float g = gamma[tid] * rsqrtf(var + BN_EPS);
    gbL[tid] = g;
    bbL[tid] = beta[tid] - mu*g;
  }
  __syncthreads();

  for (int idx = blockIdx.x*256 + tid; idx < NN*64; idx += gridDim.x*256){
    unsigned int v = A[idx];
    int c2 = idx & 63;
    float2 g = ((const float2*)gbL)[c2];
    float2 b = ((const float2*)bbL)[c2];
    float lo = frelu(bflo(v)*g.x + b.x);
    float hi = frelu(bfhi(v)*g.y + b.y);
    ((float2*)out)[idx] = make_float2(lo, hi);
  }
}

extern "C" void kernel_launch(void* const* d_in, const int* in_sizes, int n_in,
                              void* d_out, int out_size, void* d_ws, size_t ws_size,
                              hipStream_t stream){
  const float* x   = (const float*)d_in[0];
  const int*   ei  = (const int*)d_in[1];   // [2][NE], row0 = src, row1 = dst
  const float* W1  = (const float*)d_in[2];
  const float* g1  = (const float*)d_in[4];
  const float* be1 = (const float*)d_in[5];
  const float* W2  = (const float*)d_in[6];
  const float* g2  = (const float*)d_in[8];
  const float* be2 = (const float*)d_in[9];
  // b1/b2 cancel exactly inside BatchNorm (agg+b - mean(agg+b)) -> skipped.

  float* out = (float*)d_out;
  float* o1 = out;
  float* o2 = out + (size_t)NN*D;

  char* ws = (char*)d_ws;
  int*   cnt         = (int*)(ws + 0);           // 400000 B
  int*   rowStart    = (int*)(ws + 400384);      // 400000 B (padded starts)
  float* dinv        = (float*)(ws + 800768);    // 400000 B
  float* colsumB     = (float*)(ws + 1201152);   // 16384 B (2 regions x 8 banks x 256)
  int*   wgLoc       = (int*)(ws + 1217536);     // 627200 B
  unsigned long long* Wpk1 = (unsigned long long*)(ws + 1844736);  // 32768 B
  unsigned long long* Wpk2 = (unsigned long long*)(ws + 1877504);  // 32768 B
  int*   colIdx      = (int*)(ws + 1910272);     // (NE + 8*NN + 256)*4 = 9601024 B
  unsigned int* binned = (unsigned int*)(ws + 11511296);  // 6.4 MB
  unsigned int* aggb = (unsigned int*)(ws + 17911296);    // 25.6 MB (bf16 agg)
  unsigned short* h  = (unsigned short*)(ws + 43511296);  // 25.6 MB + 256 B zero row
  // total ~69.1 MB of ws

  float* colsum0 = colsumB;          // layer-1 region
  float* colsum1 = colsumB + 2048;   // layer-2 region

  // ---- build: sort+prep fused, then node build (bucket scan fused via wgLoc sums) ----
  k_sortprep<<<NWG_BIN + 3, 256, 0, stream>>>(ei, wgLoc, binned, W1, W2, Wpk1, Wpk2, colsumB, (unsigned int*)h);
  kb_node2  <<<NB, 256, 0, stream>>>(binned, wgLoc, cnt, rowStart, dinv, colIdx);

  // ---- layer 1 ----
  k_gemm1   <<<(NN + 63)/64, 256, 0, stream>>>(x, Wpk1, dinv, h);
  k_agg     <<<AGG_BLOCKS, 256, 0, stream>>>((const unsigned int*)h, dinv, rowStart, cnt, colIdx, aggb, colsum0);

  // ---- layer 2 (gemm computes gb/bb inline, applies BN+ReLU, emits o1) ----
  k_gemm2   <<<(NN + 63)/64, 256, 0, stream>>>(aggb, colsum0, g1, be1, Wpk2, dinv, h, o1);
  k_agg     <<<AGG_BLOCKS, 256, 0, stream>>>((const unsigned int*)h, dinv, rowStart, cnt, colIdx, aggb, colsum1);
  k_bnapply <<<AGG_BLOCKS, 256, 0, stream>>>(aggb, colsum1, g2, be2, o2);
}